// Round 12
// baseline (140.515 us; speedup 1.0000x reference)
//
#include <hip/hip_runtime.h>

#define SDIM 2048
#define DDIM 64
#define BHN  32
#define NQT  32

using f32x4  = __attribute__((ext_vector_type(4))) float;
using f32x16 = __attribute__((ext_vector_type(16))) float;
using bf16x8 = __attribute__((ext_vector_type(8))) __bf16;
using s16x8  = __attribute__((ext_vector_type(8))) short;

union FragU { s16x8 s; bf16x8 b; uint4 u4; };
union US8   { unsigned short u[8]; uint4 v; };
union PW    { __bf16 h[2]; unsigned int u; };

__device__ __forceinline__ unsigned short f2bf(float f) {
    unsigned int u = __builtin_bit_cast(unsigned int, f);
    u += 0x7fffu + ((u >> 16) & 1u);          // round-to-nearest-even
    return (unsigned short)(u >> 16);
}

__device__ __forceinline__ unsigned int packbf(float a, float b) {
    PW w; w.h[0] = (__bf16)a; w.h[1] = (__bf16)b; return w.u;
}

__device__ __forceinline__ void gload16(const void* g, void* l) {
    __builtin_amdgcn_global_load_lds(
        (const __attribute__((address_space(1))) void*)g,
        (__attribute__((address_space(3))) void*)l, 16, 0, 0);
}

// ---------------- pre-pass: K fp32 -> bf16 (row-major) ----------------
__global__ __launch_bounds__(256) void conv_k_kernel(
    const float* __restrict__ K, unsigned short* __restrict__ Kb)
{
    const size_t i = (size_t)blockIdx.x * 256 + threadIdx.x;   // 8 elems each
    const float4* src = (const float4*)(K + i * 8);
    float4 a = src[0], b = src[1];
    US8 o;
    o.u[0] = f2bf(a.x); o.u[1] = f2bf(a.y); o.u[2] = f2bf(a.z); o.u[3] = f2bf(a.w);
    o.u[4] = f2bf(b.x); o.u[5] = f2bf(b.y); o.u[6] = f2bf(b.z); o.u[7] = f2bf(b.w);
    *(uint4*)(Kb + i * 8) = o.v;
}

// ---------------- pre-pass: V fp32 [bh][s][d] -> V^T bf16 [bh][d][s] ----------------
__global__ __launch_bounds__(256) void conv_vt_kernel(
    const float* __restrict__ V, unsigned short* __restrict__ Vt)
{
    const int s0 = blockIdx.x * 64;
    const int bh = blockIdx.y;
    __shared__ unsigned short T[64][66];      // [s][d], padded stride
    const int t = threadIdx.x;
    {
        const int r = t >> 2, seg = t & 3;
        const float* src = V + ((size_t)bh * SDIM + s0 + r) * DDIM + seg * 16;
        float4 f0 = ((const float4*)src)[0];
        float4 f1 = ((const float4*)src)[1];
        float4 f2 = ((const float4*)src)[2];
        float4 f3 = ((const float4*)src)[3];
        float vv[16] = { f0.x, f0.y, f0.z, f0.w, f1.x, f1.y, f1.z, f1.w,
                         f2.x, f2.y, f2.z, f2.w, f3.x, f3.y, f3.z, f3.w };
        #pragma unroll
        for (int j = 0; j < 16; ++j) T[r][seg * 16 + j] = f2bf(vv[j]);
    }
    __syncthreads();
    {
        const int d = t >> 2, q = t & 3;
        US8 w0, w1;
        #pragma unroll
        for (int j = 0; j < 8; ++j) { w0.u[j] = T[q * 16 + j][d]; w1.u[j] = T[q * 16 + 8 + j][d]; }
        unsigned short* dst = Vt + ((size_t)bh * DDIM + d) * SDIM + s0 + q * 16;
        *(uint4*)dst       = w0.v;
        *(uint4*)(dst + 8) = w1.v;
    }
}

// ================= 32x32 swapped QK^T, in-register softmax (verified core) =================
__device__ __forceinline__ void compute32(
    const unsigned char* __restrict__ Kt, const unsigned char* __restrict__ Vt,
    const FragU* __restrict__ qf, f32x16& o0, f32x16& o1, f32x16& lacc,
    float& m_s, int q_lane, int q0w, int kt64, int l31, int hi)
{
    const int swz = (l31 & 7) << 4;
    const int cb  = hi * 16;

    f32x16 s0 = {}, s1 = {};
    __builtin_amdgcn_s_setprio(1);
    #pragma unroll
    for (int kc = 0; kc < 4; ++kc) {
        FragU k0f, k1f;
        k0f.u4 = *(const uint4*)&Kt[ l31       * 128 + ((kc * 32 + cb) ^ swz)];
        k1f.u4 = *(const uint4*)&Kt[(l31 + 32) * 128 + ((kc * 32 + cb) ^ swz)];
        s0 = __builtin_amdgcn_mfma_f32_32x32x16_bf16(k0f.b, qf[kc].b, s0, 0, 0, 0);
        s1 = __builtin_amdgcn_mfma_f32_32x32x16_bf16(k1f.b, qf[kc].b, s1, 0, 0, 0);
    }
    __builtin_amdgcn_s_setprio(0);

    FragU vf0[4], vf1[4];
    #pragma unroll
    for (int kc = 0; kc < 4; ++kc) {
        vf0[kc].u4 = *(const uint4*)&Vt[ l31       * 128 + ((kc * 32 + cb) ^ swz)];
        vf1[kc].u4 = *(const uint4*)&Vt[(l31 + 32) * 128 + ((kc * 32 + cb) ^ swz)];
    }

    if (kt64 + 63 > q0w) {
        #pragma unroll
        for (int r = 0; r < 16; ++r) {
            const int kl = (r & 3) + 8 * (r >> 2) + 4 * hi;
            if (kt64 + kl      > q_lane) s0[r] = -1e30f;
            if (kt64 + 32 + kl > q_lane) s1[r] = -1e30f;
        }
    }

    float m4[4];
    #pragma unroll
    for (int j = 0; j < 4; ++j)
        m4[j] = fmaxf(fmaxf(fmaxf(s0[4*j], s0[4*j+1]), fmaxf(s0[4*j+2], s0[4*j+3])),
                      fmaxf(fmaxf(s1[4*j], s1[4*j+1]), fmaxf(s1[4*j+2], s1[4*j+3])));
    float tmx = fmaxf(fmaxf(m4[0], m4[1]), fmaxf(m4[2], m4[3]));
    tmx = fmaxf(tmx, __shfl_xor(tmx, 32, 64));

    float mn = m_s;
    if (!__all(tmx <= m_s + 8.0f)) {
        mn = fmaxf(m_s, tmx);
        const float cf = exp2f(m_s - mn);
        m_s = mn;
        #pragma unroll
        for (int r = 0; r < 16; ++r) { o0[r] *= cf; o1[r] *= cf; lacc[r] *= cf; }
    }
    #pragma unroll
    for (int r = 0; r < 16; ++r) { s0[r] = exp2f(s0[r] - mn); s1[r] = exp2f(s1[r] - mn); }
    #pragma unroll
    for (int r = 0; r < 16; ++r) lacc[r] += s0[r] + s1[r];

    FragU pa[4];
    const bool lo = (hi == 0);
    #pragma unroll
    for (int h = 0; h < 2; ++h) {
        #pragma unroll
        for (int sub = 0; sub < 2; ++sub) {
            const int e = sub * 8;
            unsigned int a0, a1, b0, b1;
            if (h == 0) {
                a0 = packbf(s0[e+0], s0[e+1]); a1 = packbf(s0[e+2], s0[e+3]);
                b0 = packbf(s0[e+4], s0[e+5]); b1 = packbf(s0[e+6], s0[e+7]);
            } else {
                a0 = packbf(s1[e+0], s1[e+1]); a1 = packbf(s1[e+2], s1[e+3]);
                b0 = packbf(s1[e+4], s1[e+5]); b1 = packbf(s1[e+6], s1[e+7]);
            }
            const unsigned int ta0 = (unsigned int)__shfl_xor((int)a0, 32, 64);
            const unsigned int ta1 = (unsigned int)__shfl_xor((int)a1, 32, 64);
            const unsigned int tb0 = (unsigned int)__shfl_xor((int)b0, 32, 64);
            const unsigned int tb1 = (unsigned int)__shfl_xor((int)b1, 32, 64);
            FragU f;
            f.u4.x = lo ? a0  : tb0;
            f.u4.y = lo ? a1  : tb1;
            f.u4.z = lo ? ta0 : b0;
            f.u4.w = lo ? ta1 : b1;
            pa[h * 2 + sub] = f;
        }
    }

    __builtin_amdgcn_s_setprio(1);
    #pragma unroll
    for (int kc = 0; kc < 4; ++kc) {
        o0 = __builtin_amdgcn_mfma_f32_32x32x16_bf16(vf0[kc].b, pa[kc].b, o0, 0, 0, 0);
        o1 = __builtin_amdgcn_mfma_f32_32x32x16_bf16(vf1[kc].b, pa[kc].b, o1, 0, 0, 0);
    }
    __builtin_amdgcn_s_setprio(0);
}

// ======= v9: 8-wave blocks, kv-split x2 (flash-decoding in-block), LDS merge =======
__global__ __launch_bounds__(512, 4) void attn_fwd_v9(
    const float* __restrict__ Q, const unsigned short* __restrict__ Kbf,
    const unsigned short* __restrict__ Vtb, float* __restrict__ O)
{
    const int bh = blockIdx.y;
    // cross-block balance: CU gets block ids c and c+256 (y and y+16) -> (qt, 15-qt)
    const int qt = (bh & 16) ? (15 - (int)blockIdx.x) : (int)blockIdx.x;
    const int tid  = threadIdx.x;
    const int wid  = tid >> 6;            // 0..7
    const int wg   = wid & 3;             // strip 0..3 (32 q rows each)
    const int gid  = wid >> 2;            // kv-half 0/1
    const int lane = tid & 63;
    const int l31  = lane & 31;
    const int hi   = lane >> 5;

    // 4 staging buffers: [gid*2+parity][ K 8KB | V 8KB ]
    __shared__ unsigned char Sta[4][16384];
    __shared__ float Ml[2][4][64];

    const size_t base = (size_t)bh * SDIM * DDIM;
    const int q0w = qt * 128 + wg * 32;
    const int ql  = q0w + l31;

    const float qs = 0.125f * 1.44269504088896f;
    FragU qf[4];
    #pragma unroll
    for (int kc = 0; kc < 4; ++kc) {
        const int d0 = kc * 16 + hi * 8;
        const float* pQ = Q + base + (size_t)ql * DDIM + d0;
        float4 x = ((const float4*)pQ)[0], y = ((const float4*)pQ)[1];
        qf[kc].u4 = make_uint4(packbf(x.x*qs, x.y*qs), packbf(x.z*qs, x.w*qs),
                               packbf(y.x*qs, y.y*qs), packbf(y.z*qs, y.w*qs));
    }

    f32x16 o0 = {}, o1 = {}, lacc = {};
    float m_s = -1e30f;

    const char* Vg = (const char*)(Vtb + (size_t)bh * DDIM * SDIM);
    // stage 64-kv tile t into this group's parity buffer pb
    auto stage = [&](int t, int pb) {
        const int k0 = t * 64;
        const char* Kt = (const char*)(Kbf + ((size_t)bh * SDIM + (size_t)k0) * DDIM);
        unsigned char* buf = &Sta[gid * 2 + pb][0];
        #pragma unroll
        for (int c = 0; c < 2; ++c) {
            const int lb = wg * 2048 + c * 1024;                // wave-uniform LDS base
            const int db = lb + lane * 16;
            const int sw = ((db >> 7) & 7) << 4;
            gload16(Kt + (db ^ sw), buf + lb);
            const int d  = db >> 7;
            const int wo = (db & 127) ^ sw;
            gload16(Vg + (size_t)d * (SDIM * 2) + (size_t)k0 * 2 + wo, buf + 8192 + lb);
        }
    };

    // group 0: tiles 0..qt ; group 1: tiles qt+1..2qt+1  (qt+1 steps each)
    const int t0 = gid == 0 ? 0 : qt + 1;
    const int nst = qt + 1;
    stage(t0, 0);
    int pb = 0;
    for (int i = 0; i < nst; ++i) {
        __syncthreads();
        if (i + 1 < nst) stage(t0 + i + 1, pb ^ 1);
        const int kt64 = (t0 + i) * 64;
        if (kt64 <= q0w + 31)
            compute32(&Sta[gid * 2 + pb][0], &Sta[gid * 2 + pb][8192],
                      qf, o0, o1, lacc, m_s, ql, q0w, kt64, l31, hi);
        pb ^= 1;
    }

    // ---- per-wave row-sum of l ----
    float l16 = ((lacc[0]+lacc[1])+(lacc[2]+lacc[3])) + ((lacc[4]+lacc[5])+(lacc[6]+lacc[7]))
              + ((lacc[8]+lacc[9])+(lacc[10]+lacc[11])) + ((lacc[12]+lacc[13])+(lacc[14]+lacc[15]));
    l16 += __shfl_xor(l16, 32, 64);

    // ---- merge group 1 into group 0 via LDS (interleaved, conflict-free) ----
    __syncthreads();                       // all staging reads done; safe to reuse Sta
    float* Ob = (float*)&Sta[0][0];        // 32 KB: Ob[j*256 + wg*64 + lane], j=0..31
    if (gid == 1) {
        Ml[0][wg][lane] = m_s;
        Ml[1][wg][lane] = l16;
        #pragma unroll
        for (int j = 0; j < 16; ++j) {
            Ob[ j       * 256 + wg * 64 + lane] = o0[j];
            Ob[(j + 16) * 256 + wg * 64 + lane] = o1[j];
        }
    }
    __syncthreads();
    if (gid == 0) {
        const float m2 = Ml[0][wg][lane];
        const float l2 = Ml[1][wg][lane];
        const float m  = fmaxf(m_s, m2);
        const float c1 = exp2f(m_s - m);
        const float c2 = exp2f(m2 - m);
        const float inv = 1.f / (l16 * c1 + l2 * c2);
        const int ib = wg * 64 + lane;
        #pragma unroll
        for (int mq = 0; mq < 4; ++mq) {
            const int dm = mq * 8 + hi * 4;
            float4 w;
            w.x = (o0[4*mq+0]*c1 + Ob[(4*mq+0)*256 + ib]*c2) * inv;
            w.y = (o0[4*mq+1]*c1 + Ob[(4*mq+1)*256 + ib]*c2) * inv;
            w.z = (o0[4*mq+2]*c1 + Ob[(4*mq+2)*256 + ib]*c2) * inv;
            w.w = (o0[4*mq+3]*c1 + Ob[(4*mq+3)*256 + ib]*c2) * inv;
            *(float4*)(O + base + (size_t)ql * DDIM + dm) = w;
            w.x = (o1[4*mq+0]*c1 + Ob[(16+4*mq+0)*256 + ib]*c2) * inv;
            w.y = (o1[4*mq+1]*c1 + Ob[(16+4*mq+1)*256 + ib]*c2) * inv;
            w.z = (o1[4*mq+2]*c1 + Ob[(16+4*mq+2)*256 + ib]*c2) * inv;
            w.w = (o1[4*mq+3]*c1 + Ob[(16+4*mq+3)*256 + ib]*c2) * inv;
            *(float4*)(O + base + (size_t)ql * DDIM + 32 + dm) = w;
        }
    }
}

// ---------------- round-1-style fallback (used only if ws too small) ----------------
__global__ __launch_bounds__(256) void attn_fwd_v1(
    const float* __restrict__ Q, const float* __restrict__ K,
    const float* __restrict__ V, float* __restrict__ O)
{
    const int qt   = blockIdx.x;
    const int bh   = blockIdx.y;
    const int tid  = threadIdx.x;
    const int wid  = tid >> 6;
    const int lane = tid & 63;
    const int l15  = lane & 15;
    const int g    = lane >> 4;

    __shared__ unsigned char Klds[64 * 128];
    __shared__ unsigned char Vt[64 * 128];
    __shared__ unsigned char Pl[4][2048];

    const size_t base = (size_t)bh * SDIM * DDIM;
    const int rw0 = qt * 64 + wid * 16;

    FragU qa[2];
    {
        const float* qp = Q + base + (size_t)(rw0 + l15) * DDIM;
        #pragma unroll
        for (int kc = 0; kc < 2; ++kc) {
            const float4* pp = (const float4*)(qp + kc * 32 + g * 8);
            float4 x = pp[0], y = pp[1];
            float f[8] = { x.x, x.y, x.z, x.w, y.x, y.y, y.z, y.w };
            #pragma unroll
            for (int j = 0; j < 8; ++j) qa[kc].s[j] = (short)f2bf(f[j] * 0.125f);
        }
    }

    f32x4 o[4] = {};
    float m_i[4], l_i[4];
    #pragma unroll
    for (int i = 0; i < 4; ++i) { m_i[i] = -1e30f; l_i[i] = 0.f; }

    for (int kt = 0; kt <= qt; ++kt) {
        const int k0 = kt * 64;
        __syncthreads();
        {
            const int row = tid >> 2, seg = tid & 3;
            const float* src = K + base + (size_t)(k0 + row) * DDIM + seg * 16;
            float4 f0 = ((const float4*)src)[0];
            float4 f1 = ((const float4*)src)[1];
            float4 f2 = ((const float4*)src)[2];
            float4 f3 = ((const float4*)src)[3];
            US8 c0, c1;
            c0.u[0]=f2bf(f0.x); c0.u[1]=f2bf(f0.y); c0.u[2]=f2bf(f0.z); c0.u[3]=f2bf(f0.w);
            c0.u[4]=f2bf(f1.x); c0.u[5]=f2bf(f1.y); c0.u[6]=f2bf(f1.z); c0.u[7]=f2bf(f1.w);
            c1.u[0]=f2bf(f2.x); c1.u[1]=f2bf(f2.y); c1.u[2]=f2bf(f2.z); c1.u[3]=f2bf(f2.w);
            c1.u[4]=f2bf(f3.x); c1.u[5]=f2bf(f3.y); c1.u[6]=f2bf(f3.z); c1.u[7]=f2bf(f3.w);
            const int rb = row * 128 + seg * 32;
            const int sw = (row & 7) << 4;
            *(uint4*)&Klds[(rb)      ^ sw] = c0.v;
            *(uint4*)&Klds[(rb + 16) ^ sw] = c1.v;
        }
        {
            const int kv = tid >> 2, seg = tid & 3;
            const float* src = V + base + (size_t)(k0 + kv) * DDIM + seg * 16;
            float4 f0 = ((const float4*)src)[0];
            float4 f1 = ((const float4*)src)[1];
            float4 f2 = ((const float4*)src)[2];
            float4 f3 = ((const float4*)src)[3];
            float vv[16] = { f0.x, f0.y, f0.z, f0.w, f1.x, f1.y, f1.z, f1.w,
                             f2.x, f2.y, f2.z, f2.w, f3.x, f3.y, f3.z, f3.w };
            #pragma unroll
            for (int j = 0; j < 16; ++j) {
                const int dd = seg * 16 + j;
                const int by = dd * 128 + kv * 2;
                *(unsigned short*)&Vt[by ^ ((dd & 7) << 4)] = f2bf(vv[j]);
            }
        }
        __syncthreads();

        f32x4 s[4];
        #pragma unroll
        for (int ct = 0; ct < 4; ++ct) {
            f32x4 acc = {};
            #pragma unroll
            for (int kc = 0; kc < 2; ++kc) {
                const int row = ct * 16 + l15;
                FragU kb;
                kb.u4 = *(const uint4*)&Klds[(row * 128 + (kc * 32 + g * 8) * 2) ^ ((row & 7) << 4)];
                acc = __builtin_amdgcn_mfma_f32_16x16x32_bf16(qa[kc].b, kb.b, acc, 0, 0, 0);
            }
            s[ct] = acc;
        }
        if (kt == qt) {
            #pragma unroll
            for (int ct = 0; ct < 4; ++ct)
                #pragma unroll
                for (int i = 0; i < 4; ++i)
                    if (k0 + ct * 16 + l15 > rw0 + g * 4 + i) s[ct][i] = -1e30f;
        }
        float tm[4];
        #pragma unroll
        for (int i = 0; i < 4; ++i)
            tm[i] = fmaxf(fmaxf(s[0][i], s[1][i]), fmaxf(s[2][i], s[3][i]));
        #pragma unroll
        for (int off = 1; off < 16; off <<= 1)
            #pragma unroll
            for (int i = 0; i < 4; ++i) tm[i] = fmaxf(tm[i], __shfl_xor(tm[i], off, 64));
        float cf[4];
        #pragma unroll
        for (int i = 0; i < 4; ++i) {
            const float mn = fmaxf(m_i[i], tm[i]);
            cf[i] = __expf(m_i[i] - mn);
            m_i[i] = mn;
        }
        #pragma unroll
        for (int ct = 0; ct < 4; ++ct)
            #pragma unroll
            for (int i = 0; i < 4; ++i) s[ct][i] = __expf(s[ct][i] - m_i[i]);
        float rsv[4];
        #pragma unroll
        for (int i = 0; i < 4; ++i) rsv[i] = s[0][i] + s[1][i] + s[2][i] + s[3][i];
        #pragma unroll
        for (int off = 1; off < 16; off <<= 1)
            #pragma unroll
            for (int i = 0; i < 4; ++i) rsv[i] += __shfl_xor(rsv[i], off, 64);
        #pragma unroll
        for (int i = 0; i < 4; ++i) l_i[i] = l_i[i] * cf[i] + rsv[i];
        #pragma unroll
        for (int n = 0; n < 4; ++n)
            #pragma unroll
            for (int i = 0; i < 4; ++i) o[n][i] *= cf[i];

        unsigned char* pw = Pl[wid];
        #pragma unroll
        for (int ct = 0; ct < 4; ++ct)
            #pragma unroll
            for (int i = 0; i < 4; ++i) {
                const int row = g * 4 + i;
                const int by  = row * 128 + (ct * 16 + l15) * 2;
                *(unsigned short*)&pw[by ^ ((row & 7) << 4)] = f2bf(s[ct][i]);
            }
        asm volatile("s_waitcnt lgkmcnt(0)" ::: "memory");
        __builtin_amdgcn_sched_barrier(0);

        #pragma unroll
        for (int kc = 0; kc < 2; ++kc) {
            FragU pafr;
            pafr.u4 = *(const uint4*)&pw[(l15 * 128 + (kc * 32 + g * 8) * 2) ^ ((l15 & 7) << 4)];
            #pragma unroll
            for (int nt = 0; nt < 4; ++nt) {
                const int row = nt * 16 + l15;
                FragU vb;
                vb.u4 = *(const uint4*)&Vt[(row * 128 + (kc * 32 + g * 8) * 2) ^ ((row & 7) << 4)];
                o[nt] = __builtin_amdgcn_mfma_f32_16x16x32_bf16(pafr.b, vb.b, o[nt], 0, 0, 0);
            }
        }
    }

    #pragma unroll
    for (int i = 0; i < 4; ++i) {
        const float inv = 1.0f / l_i[i];
        float* op = O + base + (size_t)(rw0 + g * 4 + i) * DDIM;
        #pragma unroll
        for (int n = 0; n < 4; ++n) op[n * 16 + l15] = o[n][i] * inv;
    }
}

extern "C" void kernel_launch(void* const* d_in, const int* in_sizes, int n_in,
                              void* d_out, int out_size, void* d_ws, size_t ws_size,
                              hipStream_t stream) {
    const float* Q = (const float*)d_in[0];
    const float* K = (const float*)d_in[1];
    const float* V = (const float*)d_in[2];
    float* O = (float*)d_out;

    const size_t tensor_elems = (size_t)BHN * SDIM * DDIM;      // 4.19M
    const size_t need = tensor_elems * 2 * 2;                   // Kbf + Vt, bf16

    if (ws_size >= need) {
        unsigned short* Kb = (unsigned short*)d_ws;
        unsigned short* Vt = Kb + tensor_elems;
        conv_k_kernel<<<dim3((unsigned)(tensor_elems / 8 / 256)), dim3(256), 0, stream>>>(K, Kb);
        conv_vt_kernel<<<dim3(SDIM / 64, BHN), dim3(256), 0, stream>>>(V, Vt);
        attn_fwd_v9<<<dim3(16, BHN), dim3(512), 0, stream>>>(Q, Kb, Vt, O);
    } else {
        attn_fwd_v1<<<dim3(NQT, BHN), dim3(256), 0, stream>>>(Q, K, V, O);
    }
}

// Round 13
// 87.798 us; speedup vs baseline: 1.6004x; 1.6004x over previous
//
#include <hip/hip_runtime.h>

#define SDIM 2048
#define DDIM 64
#define BHN  32
#define NQT  32

using f32x4  = __attribute__((ext_vector_type(4))) float;
using f32x16 = __attribute__((ext_vector_type(16))) float;
using bf16x8 = __attribute__((ext_vector_type(8))) __bf16;
using s16x8  = __attribute__((ext_vector_type(8))) short;

union FragU { s16x8 s; bf16x8 b; uint4 u4; };
union US8   { unsigned short u[8]; uint4 v; };
union PW    { __bf16 h[2]; unsigned int u; };

__device__ __forceinline__ unsigned short f2bf(float f) {
    unsigned int u = __builtin_bit_cast(unsigned int, f);
    u += 0x7fffu + ((u >> 16) & 1u);          // round-to-nearest-even
    return (unsigned short)(u >> 16);
}

__device__ __forceinline__ unsigned int packbf(float a, float b) {
    PW w; w.h[0] = (__bf16)a; w.h[1] = (__bf16)b; return w.u;
}

__device__ __forceinline__ void gload16(const void* g, void* l) {
    __builtin_amdgcn_global_load_lds(
        (const __attribute__((address_space(1))) void*)g,
        (__attribute__((address_space(3))) void*)l, 16, 0, 0);
}

// ---------------- pre-pass: K fp32 -> bf16 (row-major) ----------------
__global__ __launch_bounds__(256) void conv_k_kernel(
    const float* __restrict__ K, unsigned short* __restrict__ Kb)
{
    const size_t i = (size_t)blockIdx.x * 256 + threadIdx.x;   // 8 elems each
    const float4* src = (const float4*)(K + i * 8);
    float4 a = src[0], b = src[1];
    US8 o;
    o.u[0] = f2bf(a.x); o.u[1] = f2bf(a.y); o.u[2] = f2bf(a.z); o.u[3] = f2bf(a.w);
    o.u[4] = f2bf(b.x); o.u[5] = f2bf(b.y); o.u[6] = f2bf(b.z); o.u[7] = f2bf(b.w);
    *(uint4*)(Kb + i * 8) = o.v;
}

// ---------------- pre-pass: V fp32 [bh][s][d] -> V^T bf16 [bh][d][s] ----------------
__global__ __launch_bounds__(256) void conv_vt_kernel(
    const float* __restrict__ V, unsigned short* __restrict__ Vt)
{
    const int s0 = blockIdx.x * 64;
    const int bh = blockIdx.y;
    __shared__ unsigned short T[64][66];      // [s][d], padded stride
    const int t = threadIdx.x;
    {
        const int r = t >> 2, seg = t & 3;
        const float* src = V + ((size_t)bh * SDIM + s0 + r) * DDIM + seg * 16;
        float4 f0 = ((const float4*)src)[0];
        float4 f1 = ((const float4*)src)[1];
        float4 f2 = ((const float4*)src)[2];
        float4 f3 = ((const float4*)src)[3];
        float vv[16] = { f0.x, f0.y, f0.z, f0.w, f1.x, f1.y, f1.z, f1.w,
                         f2.x, f2.y, f2.z, f2.w, f3.x, f3.y, f3.z, f3.w };
        #pragma unroll
        for (int j = 0; j < 16; ++j) T[r][seg * 16 + j] = f2bf(vv[j]);
    }
    __syncthreads();
    {
        const int d = t >> 2, q = t & 3;
        US8 w0, w1;
        #pragma unroll
        for (int j = 0; j < 8; ++j) { w0.u[j] = T[q * 16 + j][d]; w1.u[j] = T[q * 16 + 8 + j][d]; }
        unsigned short* dst = Vt + ((size_t)bh * DDIM + d) * SDIM + s0 + q * 16;
        *(uint4*)dst       = w0.v;
        *(uint4*)(dst + 8) = w1.v;
    }
}

// ================= 32x32 swapped QK^T, in-register softmax (verified core) =================
// V-fragment loads moved after P-pack to shorten live ranges (same data/addresses).
__device__ __forceinline__ void compute32(
    const unsigned char* __restrict__ Kt, const unsigned char* __restrict__ Vt,
    const FragU* __restrict__ qf, f32x16& o0, f32x16& o1, f32x16& lacc,
    float& m_s, int q_lane, int q0w, int kt64, int l31, int hi)
{
    const int swz = (l31 & 7) << 4;
    const int cb  = hi * 16;

    f32x16 s0 = {}, s1 = {};
    __builtin_amdgcn_s_setprio(1);
    #pragma unroll
    for (int kc = 0; kc < 4; ++kc) {
        FragU k0f, k1f;
        k0f.u4 = *(const uint4*)&Kt[ l31       * 128 + ((kc * 32 + cb) ^ swz)];
        k1f.u4 = *(const uint4*)&Kt[(l31 + 32) * 128 + ((kc * 32 + cb) ^ swz)];
        s0 = __builtin_amdgcn_mfma_f32_32x32x16_bf16(k0f.b, qf[kc].b, s0, 0, 0, 0);
        s1 = __builtin_amdgcn_mfma_f32_32x32x16_bf16(k1f.b, qf[kc].b, s1, 0, 0, 0);
    }
    __builtin_amdgcn_s_setprio(0);

    if (kt64 + 63 > q0w) {
        #pragma unroll
        for (int r = 0; r < 16; ++r) {
            const int kl = (r & 3) + 8 * (r >> 2) + 4 * hi;
            if (kt64 + kl      > q_lane) s0[r] = -1e30f;
            if (kt64 + 32 + kl > q_lane) s1[r] = -1e30f;
        }
    }

    float m4[4];
    #pragma unroll
    for (int j = 0; j < 4; ++j)
        m4[j] = fmaxf(fmaxf(fmaxf(s0[4*j], s0[4*j+1]), fmaxf(s0[4*j+2], s0[4*j+3])),
                      fmaxf(fmaxf(s1[4*j], s1[4*j+1]), fmaxf(s1[4*j+2], s1[4*j+3])));
    float tmx = fmaxf(fmaxf(m4[0], m4[1]), fmaxf(m4[2], m4[3]));
    tmx = fmaxf(tmx, __shfl_xor(tmx, 32, 64));

    float mn = m_s;
    if (!__all(tmx <= m_s + 8.0f)) {
        mn = fmaxf(m_s, tmx);
        const float cf = exp2f(m_s - mn);
        m_s = mn;
        #pragma unroll
        for (int r = 0; r < 16; ++r) { o0[r] *= cf; o1[r] *= cf; lacc[r] *= cf; }
    }
    #pragma unroll
    for (int r = 0; r < 16; ++r) { s0[r] = exp2f(s0[r] - mn); s1[r] = exp2f(s1[r] - mn); }
    #pragma unroll
    for (int r = 0; r < 16; ++r) lacc[r] += s0[r] + s1[r];

    FragU pa[4];
    const bool lo = (hi == 0);
    #pragma unroll
    for (int h = 0; h < 2; ++h) {
        #pragma unroll
        for (int sub = 0; sub < 2; ++sub) {
            const int e = sub * 8;
            unsigned int a0, a1, b0, b1;
            if (h == 0) {
                a0 = packbf(s0[e+0], s0[e+1]); a1 = packbf(s0[e+2], s0[e+3]);
                b0 = packbf(s0[e+4], s0[e+5]); b1 = packbf(s0[e+6], s0[e+7]);
            } else {
                a0 = packbf(s1[e+0], s1[e+1]); a1 = packbf(s1[e+2], s1[e+3]);
                b0 = packbf(s1[e+4], s1[e+5]); b1 = packbf(s1[e+6], s1[e+7]);
            }
            const unsigned int ta0 = (unsigned int)__shfl_xor((int)a0, 32, 64);
            const unsigned int ta1 = (unsigned int)__shfl_xor((int)a1, 32, 64);
            const unsigned int tb0 = (unsigned int)__shfl_xor((int)b0, 32, 64);
            const unsigned int tb1 = (unsigned int)__shfl_xor((int)b1, 32, 64);
            FragU f;
            f.u4.x = lo ? a0  : tb0;
            f.u4.y = lo ? a1  : tb1;
            f.u4.z = lo ? ta0 : b0;
            f.u4.w = lo ? ta1 : b1;
            pa[h * 2 + sub] = f;
        }
    }

    __builtin_amdgcn_s_setprio(1);
    #pragma unroll
    for (int kc = 0; kc < 4; ++kc) {
        FragU v0f, v1f;
        v0f.u4 = *(const uint4*)&Vt[ l31       * 128 + ((kc * 32 + cb) ^ swz)];
        v1f.u4 = *(const uint4*)&Vt[(l31 + 32) * 128 + ((kc * 32 + cb) ^ swz)];
        o0 = __builtin_amdgcn_mfma_f32_32x32x16_bf16(v0f.b, pa[kc].b, o0, 0, 0, 0);
        o1 = __builtin_amdgcn_mfma_f32_32x32x16_bf16(v1f.b, pa[kc].b, o1, 0, 0, 0);
    }
    __builtin_amdgcn_s_setprio(0);
}

// ======= v10: v9 kv-split blocks, spill-free launch bounds =======
__global__ __launch_bounds__(512, 2) void attn_fwd_v10(
    const float* __restrict__ Q, const unsigned short* __restrict__ Kbf,
    const unsigned short* __restrict__ Vtb, float* __restrict__ O)
{
    const int bh = blockIdx.y;
    // cross-round balance: CU sees blocks (x,bh) and (x,bh+16) -> qt and 15-qt
    const int qt = (bh & 16) ? (15 - (int)blockIdx.x) : (int)blockIdx.x;
    const int tid  = threadIdx.x;
    const int wid  = tid >> 6;            // 0..7
    const int wg   = wid & 3;             // strip 0..3 (32 q rows each)
    const int gid  = wid >> 2;            // kv-half 0/1
    const int lane = tid & 63;
    const int l31  = lane & 31;
    const int hi   = lane >> 5;

    // 4 staging buffers: [gid*2+parity][ K 8KB | V 8KB ]
    __shared__ unsigned char Sta[4][16384];
    __shared__ float Ml[2][4][64];

    const size_t base = (size_t)bh * SDIM * DDIM;
    const int q0w = qt * 128 + wg * 32;
    const int ql  = q0w + l31;

    const float qs = 0.125f * 1.44269504088896f;
    FragU qf[4];
    #pragma unroll
    for (int kc = 0; kc < 4; ++kc) {
        const int d0 = kc * 16 + hi * 8;
        const float* pQ = Q + base + (size_t)ql * DDIM + d0;
        float4 x = ((const float4*)pQ)[0], y = ((const float4*)pQ)[1];
        qf[kc].u4 = make_uint4(packbf(x.x*qs, x.y*qs), packbf(x.z*qs, x.w*qs),
                               packbf(y.x*qs, y.y*qs), packbf(y.z*qs, y.w*qs));
    }

    f32x16 o0 = {}, o1 = {}, lacc = {};
    float m_s = -1e30f;

    const char* Vg = (const char*)(Vtb + (size_t)bh * DDIM * SDIM);
    auto stage = [&](int t, int pb) {
        const int k0 = t * 64;
        const char* Kt = (const char*)(Kbf + ((size_t)bh * SDIM + (size_t)k0) * DDIM);
        unsigned char* buf = &Sta[gid * 2 + pb][0];
        #pragma unroll
        for (int c = 0; c < 2; ++c) {
            const int lb = wg * 2048 + c * 1024;                // wave-uniform LDS base
            const int db = lb + lane * 16;
            const int sw = ((db >> 7) & 7) << 4;
            gload16(Kt + (db ^ sw), buf + lb);
            const int d  = db >> 7;
            const int wo = (db & 127) ^ sw;
            gload16(Vg + (size_t)d * (SDIM * 2) + (size_t)k0 * 2 + wo, buf + 8192 + lb);
        }
    };

    // group 0: tiles 0..qt ; group 1: tiles qt+1..2qt+1  (qt+1 steps each)
    const int t0 = gid == 0 ? 0 : qt + 1;
    const int nst = qt + 1;
    stage(t0, 0);
    int pb = 0;
    for (int i = 0; i < nst; ++i) {
        __syncthreads();
        if (i + 1 < nst) stage(t0 + i + 1, pb ^ 1);
        const int kt64 = (t0 + i) * 64;
        if (kt64 <= q0w + 31)
            compute32(&Sta[gid * 2 + pb][0], &Sta[gid * 2 + pb][8192],
                      qf, o0, o1, lacc, m_s, ql, q0w, kt64, l31, hi);
        pb ^= 1;
    }

    // ---- per-wave row-sum of l ----
    float l16 = ((lacc[0]+lacc[1])+(lacc[2]+lacc[3])) + ((lacc[4]+lacc[5])+(lacc[6]+lacc[7]))
              + ((lacc[8]+lacc[9])+(lacc[10]+lacc[11])) + ((lacc[12]+lacc[13])+(lacc[14]+lacc[15]));
    l16 += __shfl_xor(l16, 32, 64);

    // ---- merge group 1 into group 0 via LDS (interleaved, conflict-free) ----
    __syncthreads();                       // all staging reads done; safe to reuse Sta
    float* Ob = (float*)&Sta[0][0];        // 32 KB: Ob[j*256 + wg*64 + lane], j=0..31
    if (gid == 1) {
        Ml[0][wg][lane] = m_s;
        Ml[1][wg][lane] = l16;
        #pragma unroll
        for (int j = 0; j < 16; ++j) {
            Ob[ j       * 256 + wg * 64 + lane] = o0[j];
            Ob[(j + 16) * 256 + wg * 64 + lane] = o1[j];
        }
    }
    __syncthreads();
    if (gid == 0) {
        const float m2 = Ml[0][wg][lane];
        const float l2 = Ml[1][wg][lane];
        const float m  = fmaxf(m_s, m2);
        const float c1 = exp2f(m_s - m);
        const float c2 = exp2f(m2 - m);
        const float inv = 1.f / (l16 * c1 + l2 * c2);
        const int ib = wg * 64 + lane;
        #pragma unroll
        for (int mq = 0; mq < 4; ++mq) {
            const int dm = mq * 8 + hi * 4;
            float4 w;
            w.x = (o0[4*mq+0]*c1 + Ob[(4*mq+0)*256 + ib]*c2) * inv;
            w.y = (o0[4*mq+1]*c1 + Ob[(4*mq+1)*256 + ib]*c2) * inv;
            w.z = (o0[4*mq+2]*c1 + Ob[(4*mq+2)*256 + ib]*c2) * inv;
            w.w = (o0[4*mq+3]*c1 + Ob[(4*mq+3)*256 + ib]*c2) * inv;
            *(float4*)(O + base + (size_t)ql * DDIM + dm) = w;
            w.x = (o1[4*mq+0]*c1 + Ob[(16+4*mq+0)*256 + ib]*c2) * inv;
            w.y = (o1[4*mq+1]*c1 + Ob[(16+4*mq+1)*256 + ib]*c2) * inv;
            w.z = (o1[4*mq+2]*c1 + Ob[(16+4*mq+2)*256 + ib]*c2) * inv;
            w.w = (o1[4*mq+3]*c1 + Ob[(16+4*mq+3)*256 + ib]*c2) * inv;
            *(float4*)(O + base + (size_t)ql * DDIM + 32 + dm) = w;
        }
    }
}

// ---------------- round-1-style fallback (used only if ws too small) ----------------
__global__ __launch_bounds__(256) void attn_fwd_v1(
    const float* __restrict__ Q, const float* __restrict__ K,
    const float* __restrict__ V, float* __restrict__ O)
{
    const int qt   = blockIdx.x;
    const int bh   = blockIdx.y;
    const int tid  = threadIdx.x;
    const int wid  = tid >> 6;
    const int lane = tid & 63;
    const int l15  = lane & 15;
    const int g    = lane >> 4;

    __shared__ unsigned char Klds[64 * 128];
    __shared__ unsigned char Vt[64 * 128];
    __shared__ unsigned char Pl[4][2048];

    const size_t base = (size_t)bh * SDIM * DDIM;
    const int rw0 = qt * 64 + wid * 16;

    FragU qa[2];
    {
        const float* qp = Q + base + (size_t)(rw0 + l15) * DDIM;
        #pragma unroll
        for (int kc = 0; kc < 2; ++kc) {
            const float4* pp = (const float4*)(qp + kc * 32 + g * 8);
            float4 x = pp[0], y = pp[1];
            float f[8] = { x.x, x.y, x.z, x.w, y.x, y.y, y.z, y.w };
            #pragma unroll
            for (int j = 0; j < 8; ++j) qa[kc].s[j] = (short)f2bf(f[j] * 0.125f);
        }
    }

    f32x4 o[4] = {};
    float m_i[4], l_i[4];
    #pragma unroll
    for (int i = 0; i < 4; ++i) { m_i[i] = -1e30f; l_i[i] = 0.f; }

    for (int kt = 0; kt <= qt; ++kt) {
        const int k0 = kt * 64;
        __syncthreads();
        {
            const int row = tid >> 2, seg = tid & 3;
            const float* src = K + base + (size_t)(k0 + row) * DDIM + seg * 16;
            float4 f0 = ((const float4*)src)[0];
            float4 f1 = ((const float4*)src)[1];
            float4 f2 = ((const float4*)src)[2];
            float4 f3 = ((const float4*)src)[3];
            US8 c0, c1;
            c0.u[0]=f2bf(f0.x); c0.u[1]=f2bf(f0.y); c0.u[2]=f2bf(f0.z); c0.u[3]=f2bf(f0.w);
            c0.u[4]=f2bf(f1.x); c0.u[5]=f2bf(f1.y); c0.u[6]=f2bf(f1.z); c0.u[7]=f2bf(f1.w);
            c1.u[0]=f2bf(f2.x); c1.u[1]=f2bf(f2.y); c1.u[2]=f2bf(f2.z); c1.u[3]=f2bf(f2.w);
            c1.u[4]=f2bf(f3.x); c1.u[5]=f2bf(f3.y); c1.u[6]=f2bf(f3.z); c1.u[7]=f2bf(f3.w);
            const int rb = row * 128 + seg * 32;
            const int sw = (row & 7) << 4;
            *(uint4*)&Klds[(rb)      ^ sw] = c0.v;
            *(uint4*)&Klds[(rb + 16) ^ sw] = c1.v;
        }
        {
            const int kv = tid >> 2, seg = tid & 3;
            const float* src = V + base + (size_t)(k0 + kv) * DDIM + seg * 16;
            float4 f0 = ((const float4*)src)[0];
            float4 f1 = ((const float4*)src)[1];
            float4 f2 = ((const float4*)src)[2];
            float4 f3 = ((const float4*)src)[3];
            float vv[16] = { f0.x, f0.y, f0.z, f0.w, f1.x, f1.y, f1.z, f1.w,
                             f2.x, f2.y, f2.z, f2.w, f3.x, f3.y, f3.z, f3.w };
            #pragma unroll
            for (int j = 0; j < 16; ++j) {
                const int dd = seg * 16 + j;
                const int by = dd * 128 + kv * 2;
                *(unsigned short*)&Vt[by ^ ((dd & 7) << 4)] = f2bf(vv[j]);
            }
        }
        __syncthreads();

        f32x4 s[4];
        #pragma unroll
        for (int ct = 0; ct < 4; ++ct) {
            f32x4 acc = {};
            #pragma unroll
            for (int kc = 0; kc < 2; ++kc) {
                const int row = ct * 16 + l15;
                FragU kb;
                kb.u4 = *(const uint4*)&Klds[(row * 128 + (kc * 32 + g * 8) * 2) ^ ((row & 7) << 4)];
                acc = __builtin_amdgcn_mfma_f32_16x16x32_bf16(qa[kc].b, kb.b, acc, 0, 0, 0);
            }
            s[ct] = acc;
        }
        if (kt == qt) {
            #pragma unroll
            for (int ct = 0; ct < 4; ++ct)
                #pragma unroll
                for (int i = 0; i < 4; ++i)
                    if (k0 + ct * 16 + l15 > rw0 + g * 4 + i) s[ct][i] = -1e30f;
        }
        float tm[4];
        #pragma unroll
        for (int i = 0; i < 4; ++i)
            tm[i] = fmaxf(fmaxf(s[0][i], s[1][i]), fmaxf(s[2][i], s[3][i]));
        #pragma unroll
        for (int off = 1; off < 16; off <<= 1)
            #pragma unroll
            for (int i = 0; i < 4; ++i) tm[i] = fmaxf(tm[i], __shfl_xor(tm[i], off, 64));
        float cf[4];
        #pragma unroll
        for (int i = 0; i < 4; ++i) {
            const float mn = fmaxf(m_i[i], tm[i]);
            cf[i] = __expf(m_i[i] - mn);
            m_i[i] = mn;
        }
        #pragma unroll
        for (int ct = 0; ct < 4; ++ct)
            #pragma unroll
            for (int i = 0; i < 4; ++i) s[ct][i] = __expf(s[ct][i] - m_i[i]);
        float rsv[4];
        #pragma unroll
        for (int i = 0; i < 4; ++i) rsv[i] = s[0][i] + s[1][i] + s[2][i] + s[3][i];
        #pragma unroll
        for (int off = 1; off < 16; off <<= 1)
            #pragma unroll
            for (int i = 0; i < 4; ++i) rsv[i] += __shfl_xor(rsv[i], off, 64);
        #pragma unroll
        for (int i = 0; i < 4; ++i) l_i[i] = l_i[i] * cf[i] + rsv[i];
        #pragma unroll
        for (int n = 0; n < 4; ++n)
            #pragma unroll
            for (int i = 0; i < 4; ++i) o[n][i] *= cf[i];

        unsigned char* pw = Pl[wid];
        #pragma unroll
        for (int ct = 0; ct < 4; ++ct)
            #pragma unroll
            for (int i = 0; i < 4; ++i) {
                const int row = g * 4 + i;
                const int by  = row * 128 + (ct * 16 + l15) * 2;
                *(unsigned short*)&pw[by ^ ((row & 7) << 4)] = f2bf(s[ct][i]);
            }
        asm volatile("s_waitcnt lgkmcnt(0)" ::: "memory");
        __builtin_amdgcn_sched_barrier(0);

        #pragma unroll
        for (int kc = 0; kc < 2; ++kc) {
            FragU pafr;
            pafr.u4 = *(const uint4*)&pw[(l15 * 128 + (kc * 32 + g * 8) * 2) ^ ((l15 & 7) << 4)];
            #pragma unroll
            for (int nt = 0; nt < 4; ++nt) {
                const int row = nt * 16 + l15;
                FragU vb;
                vb.u4 = *(const uint4*)&Vt[(row * 128 + (kc * 32 + g * 8) * 2) ^ ((row & 7) << 4)];
                o[nt] = __builtin_amdgcn_mfma_f32_16x16x32_bf16(pafr.b, vb.b, o[nt], 0, 0, 0);
            }
        }
    }

    #pragma unroll
    for (int i = 0; i < 4; ++i) {
        const float inv = 1.0f / l_i[i];
        float* op = O + base + (size_t)(rw0 + g * 4 + i) * DDIM;
        #pragma unroll
        for (int n = 0; n < 4; ++n) op[n * 16 + l15] = o[n][i] * inv;
    }
}

extern "C" void kernel_launch(void* const* d_in, const int* in_sizes, int n_in,
                              void* d_out, int out_size, void* d_ws, size_t ws_size,
                              hipStream_t stream) {
    const float* Q = (const float*)d_in[0];
    const float* K = (const float*)d_in[1];
    const float* V = (const float*)d_in[2];
    float* O = (float*)d_out;

    const size_t tensor_elems = (size_t)BHN * SDIM * DDIM;      // 4.19M
    const size_t need = tensor_elems * 2 * 2;                   // Kbf + Vt, bf16

    if (ws_size >= need) {
        unsigned short* Kb = (unsigned short*)d_ws;
        unsigned short* Vt = Kb + tensor_elems;
        conv_k_kernel<<<dim3((unsigned)(tensor_elems / 8 / 256)), dim3(256), 0, stream>>>(K, Kb);
        conv_vt_kernel<<<dim3(SDIM / 64, BHN), dim3(256), 0, stream>>>(V, Vt);
        attn_fwd_v10<<<dim3(16, BHN), dim3(512), 0, stream>>>(Q, Kb, Vt, O);
    } else {
        attn_fwd_v1<<<dim3(NQT, BHN), dim3(256), 0, stream>>>(Q, K, V, O);
    }
}

// Round 14
// 71.562 us; speedup vs baseline: 1.9635x; 1.2269x over previous
//
#include <hip/hip_runtime.h>

#define SDIM 2048
#define DDIM 64
#define BHN  32
#define NQT  32

using f32x4  = __attribute__((ext_vector_type(4))) float;
using f32x16 = __attribute__((ext_vector_type(16))) float;
using bf16x8 = __attribute__((ext_vector_type(8))) __bf16;
using s16x8  = __attribute__((ext_vector_type(8))) short;

union FragU { s16x8 s; bf16x8 b; uint4 u4; };
union US8   { unsigned short u[8]; uint4 v; };
union PW    { __bf16 h[2]; unsigned int u; };

__device__ __forceinline__ unsigned short f2bf(float f) {
    unsigned int u = __builtin_bit_cast(unsigned int, f);
    u += 0x7fffu + ((u >> 16) & 1u);          // round-to-nearest-even
    return (unsigned short)(u >> 16);
}

__device__ __forceinline__ unsigned int packbf(float a, float b) {
    PW w; w.h[0] = (__bf16)a; w.h[1] = (__bf16)b; return w.u;
}

__device__ __forceinline__ void gload16(const void* g, void* l) {
    __builtin_amdgcn_global_load_lds(
        (const __attribute__((address_space(1))) void*)g,
        (__attribute__((address_space(3))) void*)l, 16, 0, 0);
}

// ---------------- pre-pass: K fp32 -> bf16 (row-major) ----------------
__global__ __launch_bounds__(256) void conv_k_kernel(
    const float* __restrict__ K, unsigned short* __restrict__ Kb)
{
    const size_t i = (size_t)blockIdx.x * 256 + threadIdx.x;   // 8 elems each
    const float4* src = (const float4*)(K + i * 8);
    float4 a = src[0], b = src[1];
    US8 o;
    o.u[0] = f2bf(a.x); o.u[1] = f2bf(a.y); o.u[2] = f2bf(a.z); o.u[3] = f2bf(a.w);
    o.u[4] = f2bf(b.x); o.u[5] = f2bf(b.y); o.u[6] = f2bf(b.z); o.u[7] = f2bf(b.w);
    *(uint4*)(Kb + i * 8) = o.v;
}

// ---------------- pre-pass: V fp32 [bh][s][d] -> V^T bf16 [bh][d][s] ----------------
__global__ __launch_bounds__(256) void conv_vt_kernel(
    const float* __restrict__ V, unsigned short* __restrict__ Vt)
{
    const int s0 = blockIdx.x * 64;
    const int bh = blockIdx.y;
    __shared__ unsigned short T[64][66];      // [s][d], padded stride
    const int t = threadIdx.x;
    {
        const int r = t >> 2, seg = t & 3;
        const float* src = V + ((size_t)bh * SDIM + s0 + r) * DDIM + seg * 16;
        float4 f0 = ((const float4*)src)[0];
        float4 f1 = ((const float4*)src)[1];
        float4 f2 = ((const float4*)src)[2];
        float4 f3 = ((const float4*)src)[3];
        float vv[16] = { f0.x, f0.y, f0.z, f0.w, f1.x, f1.y, f1.z, f1.w,
                         f2.x, f2.y, f2.z, f2.w, f3.x, f3.y, f3.z, f3.w };
        #pragma unroll
        for (int j = 0; j < 16; ++j) T[r][seg * 16 + j] = f2bf(vv[j]);
    }
    __syncthreads();
    {
        const int d = t >> 2, q = t & 3;
        US8 w0, w1;
        #pragma unroll
        for (int j = 0; j < 8; ++j) { w0.u[j] = T[q * 16 + j][d]; w1.u[j] = T[q * 16 + 8 + j][d]; }
        unsigned short* dst = Vt + ((size_t)bh * DDIM + d) * SDIM + s0 + q * 16;
        *(uint4*)dst       = w0.v;
        *(uint4*)(dst + 8) = w1.v;
    }
}

// ================= 32x32 swapped QK^T, in-register softmax (verified core) =================
__device__ __forceinline__ void compute32(
    const unsigned char* __restrict__ Kt, const unsigned char* __restrict__ Vt,
    const FragU* __restrict__ qf, f32x16& o0, f32x16& o1, f32x16& lacc,
    float& m_s, int q_lane, int q0w, int kt64, int l31, int hi)
{
    const int swz = (l31 & 7) << 4;
    const int cb  = hi * 16;

    f32x16 s0 = {}, s1 = {};
    __builtin_amdgcn_s_setprio(1);
    #pragma unroll
    for (int kc = 0; kc < 4; ++kc) {
        FragU k0f, k1f;
        k0f.u4 = *(const uint4*)&Kt[ l31       * 128 + ((kc * 32 + cb) ^ swz)];
        k1f.u4 = *(const uint4*)&Kt[(l31 + 32) * 128 + ((kc * 32 + cb) ^ swz)];
        s0 = __builtin_amdgcn_mfma_f32_32x32x16_bf16(k0f.b, qf[kc].b, s0, 0, 0, 0);
        s1 = __builtin_amdgcn_mfma_f32_32x32x16_bf16(k1f.b, qf[kc].b, s1, 0, 0, 0);
    }
    __builtin_amdgcn_s_setprio(0);

    if (kt64 + 63 > q0w) {
        #pragma unroll
        for (int r = 0; r < 16; ++r) {
            const int kl = (r & 3) + 8 * (r >> 2) + 4 * hi;
            if (kt64 + kl      > q_lane) s0[r] = -1e30f;
            if (kt64 + 32 + kl > q_lane) s1[r] = -1e30f;
        }
    }

    float m4[4];
    #pragma unroll
    for (int j = 0; j < 4; ++j)
        m4[j] = fmaxf(fmaxf(fmaxf(s0[4*j], s0[4*j+1]), fmaxf(s0[4*j+2], s0[4*j+3])),
                      fmaxf(fmaxf(s1[4*j], s1[4*j+1]), fmaxf(s1[4*j+2], s1[4*j+3])));
    float tmx = fmaxf(fmaxf(m4[0], m4[1]), fmaxf(m4[2], m4[3]));
    tmx = fmaxf(tmx, __shfl_xor(tmx, 32, 64));

    float mn = m_s;
    if (!__all(tmx <= m_s + 8.0f)) {
        mn = fmaxf(m_s, tmx);
        const float cf = exp2f(m_s - mn);
        m_s = mn;
        #pragma unroll
        for (int r = 0; r < 16; ++r) { o0[r] *= cf; o1[r] *= cf; lacc[r] *= cf; }
    }
    #pragma unroll
    for (int r = 0; r < 16; ++r) { s0[r] = exp2f(s0[r] - mn); s1[r] = exp2f(s1[r] - mn); }
    #pragma unroll
    for (int r = 0; r < 16; ++r) lacc[r] += s0[r] + s1[r];

    FragU pa[4];
    const bool lo = (hi == 0);
    #pragma unroll
    for (int h = 0; h < 2; ++h) {
        #pragma unroll
        for (int sub = 0; sub < 2; ++sub) {
            const int e = sub * 8;
            unsigned int a0, a1, b0, b1;
            if (h == 0) {
                a0 = packbf(s0[e+0], s0[e+1]); a1 = packbf(s0[e+2], s0[e+3]);
                b0 = packbf(s0[e+4], s0[e+5]); b1 = packbf(s0[e+6], s0[e+7]);
            } else {
                a0 = packbf(s1[e+0], s1[e+1]); a1 = packbf(s1[e+2], s1[e+3]);
                b0 = packbf(s1[e+4], s1[e+5]); b1 = packbf(s1[e+6], s1[e+7]);
            }
            const unsigned int ta0 = (unsigned int)__shfl_xor((int)a0, 32, 64);
            const unsigned int ta1 = (unsigned int)__shfl_xor((int)a1, 32, 64);
            const unsigned int tb0 = (unsigned int)__shfl_xor((int)b0, 32, 64);
            const unsigned int tb1 = (unsigned int)__shfl_xor((int)b1, 32, 64);
            FragU f;
            f.u4.x = lo ? a0  : tb0;
            f.u4.y = lo ? a1  : tb1;
            f.u4.z = lo ? ta0 : b0;
            f.u4.w = lo ? ta1 : b1;
            pa[h * 2 + sub] = f;
        }
    }

    __builtin_amdgcn_s_setprio(1);
    #pragma unroll
    for (int kc = 0; kc < 4; ++kc) {
        FragU v0f, v1f;
        v0f.u4 = *(const uint4*)&Vt[ l31       * 128 + ((kc * 32 + cb) ^ swz)];
        v1f.u4 = *(const uint4*)&Vt[(l31 + 32) * 128 + ((kc * 32 + cb) ^ swz)];
        o0 = __builtin_amdgcn_mfma_f32_32x32x16_bf16(v0f.b, pa[kc].b, o0, 0, 0, 0);
        o1 = __builtin_amdgcn_mfma_f32_32x32x16_bf16(v1f.b, pa[kc].b, o1, 0, 0, 0);
    }
    __builtin_amdgcn_s_setprio(0);
}

// ======= v11: 8-wave blocks, dual-tile (A=bx, B=15-bx), 17/17 kv-unit split =======
// All 256 blocks run EXACTLY 17 uniform steps; 2 waves/SIMD computing throughout.
__global__ __launch_bounds__(512, 2) void attn_fwd_v11(
    const float* __restrict__ Q, const unsigned short* __restrict__ Kbf,
    const unsigned short* __restrict__ Vtb, float* __restrict__ O)
{
    const int bx = blockIdx.x;            // 0..7
    const int bh = blockIdx.y;
    const int qtA = bx;                   // 128-row tiles
    const int qtB = 15 - bx;
    const int nB  = 32 - 2 * bx;          // B kv-tiles (18..32); nA = 34-nB
    const int tid  = threadIdx.x;
    const int wid  = tid >> 6;            // 0..7
    const int wg   = wid & 3;             // strip 0..3 (32 q rows)
    const int gid  = wid >> 2;            // unit-half 0/1
    const int lane = tid & 63;
    const int l31  = lane & 31;
    const int hi   = lane >> 5;

    __shared__ unsigned char Sta[4][16384];   // [gid*2+parity][ K 8KB | V 8KB ]
    __shared__ float Ml[2][4][64];

    const size_t base = (size_t)bh * SDIM * DDIM;
    const int q0A = qtA * 128 + wg * 32;
    const int q0B = qtB * 128 + wg * 32;
    const int qAl = q0A + l31, qBl = q0B + l31;

    const float qs = 0.125f * 1.44269504088896f;
    FragU qfA[4], qfB[4];
    #pragma unroll
    for (int kc = 0; kc < 4; ++kc) {
        const int d0 = kc * 16 + hi * 8;
        const float* pA = Q + base + (size_t)qAl * DDIM + d0;
        const float* pB = Q + base + (size_t)qBl * DDIM + d0;
        float4 xa = ((const float4*)pA)[0], ya = ((const float4*)pA)[1];
        float4 xb = ((const float4*)pB)[0], yb = ((const float4*)pB)[1];
        qfA[kc].u4 = make_uint4(packbf(xa.x*qs, xa.y*qs), packbf(xa.z*qs, xa.w*qs),
                                packbf(ya.x*qs, ya.y*qs), packbf(ya.z*qs, ya.w*qs));
        qfB[kc].u4 = make_uint4(packbf(xb.x*qs, xb.y*qs), packbf(xb.z*qs, xb.w*qs),
                                packbf(yb.x*qs, yb.y*qs), packbf(yb.z*qs, yb.w*qs));
    }

    f32x16 oA0 = {}, oA1 = {}, laccA = {};
    f32x16 oB0 = {}, oB1 = {}, laccB = {};
    float mA = -1e30f, mB = -1e30f;

    const char* Vg = (const char*)(Vtb + (size_t)bh * DDIM * SDIM);
    auto stage = [&](int k0, int pb) {        // k0 = kv row base
        const char* Kt = (const char*)(Kbf + ((size_t)bh * SDIM + (size_t)k0) * DDIM);
        unsigned char* buf = &Sta[gid * 2 + pb][0];
        #pragma unroll
        for (int c = 0; c < 2; ++c) {
            const int lb = wg * 2048 + c * 1024;               // wave-uniform LDS base
            const int db = lb + lane * 16;
            const int sw = ((db >> 7) & 7) << 4;
            gload16(Kt + (db ^ sw), buf + lb);
            const int d  = db >> 7;
            const int wo = (db & 127) ^ sw;
            gload16(Vg + (size_t)d * (SDIM * 2) + (size_t)k0 * 2 + wo, buf + 8192 + lb);
        }
    };

    // unit u (0..33): u < nB -> tile B kv-tile u ; else tile A kv-tile u-nB.
    const int ubase = gid * 17;
    stage(((ubase < nB) ? ubase : ubase - nB) * 64, 0);
    int pb = 0;
    for (int i = 0; i < 17; ++i) {
        __syncthreads();                       // staged loads landed; prior reads done
        if (i + 1 < 17) {
            const int un = ubase + i + 1;
            stage(((un < nB) ? un : un - nB) * 64, pb ^ 1);
        }
        const int u = ubase + i;
        const unsigned char* Kb_ = &Sta[gid * 2 + pb][0];
        const unsigned char* Vb_ = &Sta[gid * 2 + pb][8192];
        if (u < nB) {
            const int kt64 = u * 64;
            if (kt64 <= q0B + 31)
                compute32(Kb_, Vb_, qfB, oB0, oB1, laccB, mB, qBl, q0B, kt64, l31, hi);
        } else {
            const int kt64 = (u - nB) * 64;
            if (kt64 <= q0A + 31)
                compute32(Kb_, Vb_, qfA, oA0, oA1, laccA, mA, qAl, q0A, kt64, l31, hi);
        }
        pb ^= 1;
    }

    // ---- per-wave l row-sums ----
    float lB = ((laccB[0]+laccB[1])+(laccB[2]+laccB[3])) + ((laccB[4]+laccB[5])+(laccB[6]+laccB[7]))
             + ((laccB[8]+laccB[9])+(laccB[10]+laccB[11])) + ((laccB[12]+laccB[13])+(laccB[14]+laccB[15]));
    lB += __shfl_xor(lB, 32, 64);
    float lA = ((laccA[0]+laccA[1])+(laccA[2]+laccA[3])) + ((laccA[4]+laccA[5])+(laccA[6]+laccA[7]))
             + ((laccA[8]+laccA[9])+(laccA[10]+laccA[11])) + ((laccA[12]+laccA[13])+(laccA[14]+laccA[15]));
    lA += __shfl_xor(lA, 32, 64);

    float* Ob = (float*)&Sta[0][0];           // 32 KB scratch for one tile's partial O
    const int ib = wg * 64 + lane;

    // ---- merge tile B ----
    __syncthreads();
    if (gid == 1) {
        Ml[0][wg][lane] = mB;
        Ml[1][wg][lane] = lB;
        #pragma unroll
        for (int j = 0; j < 16; ++j) {
            Ob[ j       * 256 + ib] = oB0[j];
            Ob[(j + 16) * 256 + ib] = oB1[j];
        }
    }
    __syncthreads();
    if (gid == 0) {
        const float m2 = Ml[0][wg][lane];
        const float l2 = Ml[1][wg][lane];
        const float m  = fmaxf(mB, m2);
        const float c1 = exp2f(mB - m);
        const float c2 = exp2f(m2 - m);
        const float inv = 1.f / (lB * c1 + l2 * c2);
        #pragma unroll
        for (int mq = 0; mq < 4; ++mq) {
            const int dm = mq * 8 + hi * 4;
            float4 w;
            w.x = (oB0[4*mq+0]*c1 + Ob[(4*mq+0)*256 + ib]*c2) * inv;
            w.y = (oB0[4*mq+1]*c1 + Ob[(4*mq+1)*256 + ib]*c2) * inv;
            w.z = (oB0[4*mq+2]*c1 + Ob[(4*mq+2)*256 + ib]*c2) * inv;
            w.w = (oB0[4*mq+3]*c1 + Ob[(4*mq+3)*256 + ib]*c2) * inv;
            *(float4*)(O + base + (size_t)qBl * DDIM + dm) = w;
            w.x = (oB1[4*mq+0]*c1 + Ob[(16+4*mq+0)*256 + ib]*c2) * inv;
            w.y = (oB1[4*mq+1]*c1 + Ob[(16+4*mq+1)*256 + ib]*c2) * inv;
            w.z = (oB1[4*mq+2]*c1 + Ob[(16+4*mq+2)*256 + ib]*c2) * inv;
            w.w = (oB1[4*mq+3]*c1 + Ob[(16+4*mq+3)*256 + ib]*c2) * inv;
            *(float4*)(O + base + (size_t)qBl * DDIM + 32 + dm) = w;
        }
    }

    // ---- merge tile A ----
    __syncthreads();
    if (gid == 1) {
        Ml[0][wg][lane] = mA;
        Ml[1][wg][lane] = lA;
        #pragma unroll
        for (int j = 0; j < 16; ++j) {
            Ob[ j       * 256 + ib] = oA0[j];
            Ob[(j + 16) * 256 + ib] = oA1[j];
        }
    }
    __syncthreads();
    if (gid == 0) {
        const float m2 = Ml[0][wg][lane];
        const float l2 = Ml[1][wg][lane];
        const float m  = fmaxf(mA, m2);
        const float c1 = exp2f(mA - m);
        const float c2 = exp2f(m2 - m);
        const float inv = 1.f / (lA * c1 + l2 * c2);
        #pragma unroll
        for (int mq = 0; mq < 4; ++mq) {
            const int dm = mq * 8 + hi * 4;
            float4 w;
            w.x = (oA0[4*mq+0]*c1 + Ob[(4*mq+0)*256 + ib]*c2) * inv;
            w.y = (oA0[4*mq+1]*c1 + Ob[(4*mq+1)*256 + ib]*c2) * inv;
            w.z = (oA0[4*mq+2]*c1 + Ob[(4*mq+2)*256 + ib]*c2) * inv;
            w.w = (oA0[4*mq+3]*c1 + Ob[(4*mq+3)*256 + ib]*c2) * inv;
            *(float4*)(O + base + (size_t)qAl * DDIM + dm) = w;
            w.x = (oA1[4*mq+0]*c1 + Ob[(16+4*mq+0)*256 + ib]*c2) * inv;
            w.y = (oA1[4*mq+1]*c1 + Ob[(16+4*mq+1)*256 + ib]*c2) * inv;
            w.z = (oA1[4*mq+2]*c1 + Ob[(16+4*mq+2)*256 + ib]*c2) * inv;
            w.w = (oA1[4*mq+3]*c1 + Ob[(16+4*mq+3)*256 + ib]*c2) * inv;
            *(float4*)(O + base + (size_t)qAl * DDIM + 32 + dm) = w;
        }
    }
}

// ---------------- round-1-style fallback (used only if ws too small) ----------------
__global__ __launch_bounds__(256) void attn_fwd_v1(
    const float* __restrict__ Q, const float* __restrict__ K,
    const float* __restrict__ V, float* __restrict__ O)
{
    const int qt   = blockIdx.x;
    const int bh   = blockIdx.y;
    const int tid  = threadIdx.x;
    const int wid  = tid >> 6;
    const int lane = tid & 63;
    const int l15  = lane & 15;
    const int g    = lane >> 4;

    __shared__ unsigned char Klds[64 * 128];
    __shared__ unsigned char Vt[64 * 128];
    __shared__ unsigned char Pl[4][2048];

    const size_t base = (size_t)bh * SDIM * DDIM;
    const int rw0 = qt * 64 + wid * 16;

    FragU qa[2];
    {
        const float* qp = Q + base + (size_t)(rw0 + l15) * DDIM;
        #pragma unroll
        for (int kc = 0; kc < 2; ++kc) {
            const float4* pp = (const float4*)(qp + kc * 32 + g * 8);
            float4 x = pp[0], y = pp[1];
            float f[8] = { x.x, x.y, x.z, x.w, y.x, y.y, y.z, y.w };
            #pragma unroll
            for (int j = 0; j < 8; ++j) qa[kc].s[j] = (short)f2bf(f[j] * 0.125f);
        }
    }

    f32x4 o[4] = {};
    float m_i[4], l_i[4];
    #pragma unroll
    for (int i = 0; i < 4; ++i) { m_i[i] = -1e30f; l_i[i] = 0.f; }

    for (int kt = 0; kt <= qt; ++kt) {
        const int k0 = kt * 64;
        __syncthreads();
        {
            const int row = tid >> 2, seg = tid & 3;
            const float* src = K + base + (size_t)(k0 + row) * DDIM + seg * 16;
            float4 f0 = ((const float4*)src)[0];
            float4 f1 = ((const float4*)src)[1];
            float4 f2 = ((const float4*)src)[2];
            float4 f3 = ((const float4*)src)[3];
            US8 c0, c1;
            c0.u[0]=f2bf(f0.x); c0.u[1]=f2bf(f0.y); c0.u[2]=f2bf(f0.z); c0.u[3]=f2bf(f0.w);
            c0.u[4]=f2bf(f1.x); c0.u[5]=f2bf(f1.y); c0.u[6]=f2bf(f1.z); c0.u[7]=f2bf(f1.w);
            c1.u[0]=f2bf(f2.x); c1.u[1]=f2bf(f2.y); c1.u[2]=f2bf(f2.z); c1.u[3]=f2bf(f2.w);
            c1.u[4]=f2bf(f3.x); c1.u[5]=f2bf(f3.y); c1.u[6]=f2bf(f3.z); c1.u[7]=f2bf(f3.w);
            const int rb = row * 128 + seg * 32;
            const int sw = (row & 7) << 4;
            *(uint4*)&Klds[(rb)      ^ sw] = c0.v;
            *(uint4*)&Klds[(rb + 16) ^ sw] = c1.v;
        }
        {
            const int kv = tid >> 2, seg = tid & 3;
            const float* src = V + base + (size_t)(k0 + kv) * DDIM + seg * 16;
            float4 f0 = ((const float4*)src)[0];
            float4 f1 = ((const float4*)src)[1];
            float4 f2 = ((const float4*)src)[2];
            float4 f3 = ((const float4*)src)[3];
            float vv[16] = { f0.x, f0.y, f0.z, f0.w, f1.x, f1.y, f1.z, f1.w,
                             f2.x, f2.y, f2.z, f2.w, f3.x, f3.y, f3.z, f3.w };
            #pragma unroll
            for (int j = 0; j < 16; ++j) {
                const int dd = seg * 16 + j;
                const int by = dd * 128 + kv * 2;
                *(unsigned short*)&Vt[by ^ ((dd & 7) << 4)] = f2bf(vv[j]);
            }
        }
        __syncthreads();

        f32x4 s[4];
        #pragma unroll
        for (int ct = 0; ct < 4; ++ct) {
            f32x4 acc = {};
            #pragma unroll
            for (int kc = 0; kc < 2; ++kc) {
                const int row = ct * 16 + l15;
                FragU kb;
                kb.u4 = *(const uint4*)&Klds[(row * 128 + (kc * 32 + g * 8) * 2) ^ ((row & 7) << 4)];
                acc = __builtin_amdgcn_mfma_f32_16x16x32_bf16(qa[kc].b, kb.b, acc, 0, 0, 0);
            }
            s[ct] = acc;
        }
        if (kt == qt) {
            #pragma unroll
            for (int ct = 0; ct < 4; ++ct)
                #pragma unroll
                for (int i = 0; i < 4; ++i)
                    if (k0 + ct * 16 + l15 > rw0 + g * 4 + i) s[ct][i] = -1e30f;
        }
        float tm[4];
        #pragma unroll
        for (int i = 0; i < 4; ++i)
            tm[i] = fmaxf(fmaxf(s[0][i], s[1][i]), fmaxf(s[2][i], s[3][i]));
        #pragma unroll
        for (int off = 1; off < 16; off <<= 1)
            #pragma unroll
            for (int i = 0; i < 4; ++i) tm[i] = fmaxf(tm[i], __shfl_xor(tm[i], off, 64));
        float cf[4];
        #pragma unroll
        for (int i = 0; i < 4; ++i) {
            const float mn = fmaxf(m_i[i], tm[i]);
            cf[i] = __expf(m_i[i] - mn);
            m_i[i] = mn;
        }
        #pragma unroll
        for (int ct = 0; ct < 4; ++ct)
            #pragma unroll
            for (int i = 0; i < 4; ++i) s[ct][i] = __expf(s[ct][i] - m_i[i]);
        float rsv[4];
        #pragma unroll
        for (int i = 0; i < 4; ++i) rsv[i] = s[0][i] + s[1][i] + s[2][i] + s[3][i];
        #pragma unroll
        for (int off = 1; off < 16; off <<= 1)
            #pragma unroll
            for (int i = 0; i < 4; ++i) rsv[i] += __shfl_xor(rsv[i], off, 64);
        #pragma unroll
        for (int i = 0; i < 4; ++i) l_i[i] = l_i[i] * cf[i] + rsv[i];
        #pragma unroll
        for (int n = 0; n < 4; ++n)
            #pragma unroll
            for (int i = 0; i < 4; ++i) o[n][i] *= cf[i];

        unsigned char* pw = Pl[wid];
        #pragma unroll
        for (int ct = 0; ct < 4; ++ct)
            #pragma unroll
            for (int i = 0; i < 4; ++i) {
                const int row = g * 4 + i;
                const int by  = row * 128 + (ct * 16 + l15) * 2;
                *(unsigned short*)&pw[by ^ ((row & 7) << 4)] = f2bf(s[ct][i]);
            }
        asm volatile("s_waitcnt lgkmcnt(0)" ::: "memory");
        __builtin_amdgcn_sched_barrier(0);

        #pragma unroll
        for (int kc = 0; kc < 2; ++kc) {
            FragU pafr;
            pafr.u4 = *(const uint4*)&pw[(l15 * 128 + (kc * 32 + g * 8) * 2) ^ ((l15 & 7) << 4)];
            #pragma unroll
            for (int nt = 0; nt < 4; ++nt) {
                const int row = nt * 16 + l15;
                FragU vb;
                vb.u4 = *(const uint4*)&Vt[(row * 128 + (kc * 32 + g * 8) * 2) ^ ((row & 7) << 4)];
                o[nt] = __builtin_amdgcn_mfma_f32_16x16x32_bf16(pafr.b, vb.b, o[nt], 0, 0, 0);
            }
        }
    }

    #pragma unroll
    for (int i = 0; i < 4; ++i) {
        const float inv = 1.0f / l_i[i];
        float* op = O + base + (size_t)(rw0 + g * 4 + i) * DDIM;
        #pragma unroll
        for (int n = 0; n < 4; ++n) op[n * 16 + l15] = o[n][i] * inv;
    }
}

extern "C" void kernel_launch(void* const* d_in, const int* in_sizes, int n_in,
                              void* d_out, int out_size, void* d_ws, size_t ws_size,
                              hipStream_t stream) {
    const float* Q = (const float*)d_in[0];
    const float* K = (const float*)d_in[1];
    const float* V = (const float*)d_in[2];
    float* O = (float*)d_out;

    const size_t tensor_elems = (size_t)BHN * SDIM * DDIM;      // 4.19M
    const size_t need = tensor_elems * 2 * 2;                   // Kbf + Vt, bf16

    if (ws_size >= need) {
        unsigned short* Kb = (unsigned short*)d_ws;
        unsigned short* Vt = Kb + tensor_elems;
        conv_k_kernel<<<dim3((unsigned)(tensor_elems / 8 / 256)), dim3(256), 0, stream>>>(K, Kb);
        conv_vt_kernel<<<dim3(SDIM / 64, BHN), dim3(256), 0, stream>>>(V, Vt);
        attn_fwd_v11<<<dim3(8, BHN), dim3(512), 0, stream>>>(Q, Kb, Vt, O);
    } else {
        attn_fwd_v1<<<dim3(NQT, BHN), dim3(256), 0, stream>>>(Q, K, V, O);
    }
}

// Round 16
// 64.269 us; speedup vs baseline: 2.1864x; 1.1135x over previous
//
#include <hip/hip_runtime.h>

#define SDIM 2048
#define DDIM 64
#define BHN  32
#define NQT  32

using f32x4  = __attribute__((ext_vector_type(4))) float;
using f32x16 = __attribute__((ext_vector_type(16))) float;
using bf16x8 = __attribute__((ext_vector_type(8))) __bf16;
using s16x8  = __attribute__((ext_vector_type(8))) short;

union FragU { s16x8 s; bf16x8 b; uint4 u4; };
union US8   { unsigned short u[8]; uint4 v; };
union PW    { __bf16 h[2]; unsigned int u; };

__device__ __forceinline__ unsigned short f2bf(float f) {
    unsigned int u = __builtin_bit_cast(unsigned int, f);
    u += 0x7fffu + ((u >> 16) & 1u);          // round-to-nearest-even
    return (unsigned short)(u >> 16);
}

__device__ __forceinline__ unsigned int packbf(float a, float b) {
    PW w; w.h[0] = (__bf16)a; w.h[1] = (__bf16)b; return w.u;
}

// HW transcendental: v_exp_f32 computes 2^x directly (1 instruction).
__device__ __forceinline__ float fexp2(float x) { return __builtin_amdgcn_exp2f(x); }

__device__ __forceinline__ void gload16(const void* g, void* l) {
    __builtin_amdgcn_global_load_lds(
        (const __attribute__((address_space(1))) void*)g,
        (__attribute__((address_space(3))) void*)l, 16, 0, 0);
}

// ---------------- pre-pass: K fp32 -> bf16 (row-major) ----------------
__global__ __launch_bounds__(256) void conv_k_kernel(
    const float* __restrict__ K, unsigned short* __restrict__ Kb)
{
    const size_t i = (size_t)blockIdx.x * 256 + threadIdx.x;   // 8 elems each
    const float4* src = (const float4*)(K + i * 8);
    float4 a = src[0], b = src[1];
    US8 o;
    o.u[0] = f2bf(a.x); o.u[1] = f2bf(a.y); o.u[2] = f2bf(a.z); o.u[3] = f2bf(a.w);
    o.u[4] = f2bf(b.x); o.u[5] = f2bf(b.y); o.u[6] = f2bf(b.z); o.u[7] = f2bf(b.w);
    *(uint4*)(Kb + i * 8) = o.v;
}

// ---------------- pre-pass: V fp32 [bh][s][d] -> V^T bf16 [bh][d][s] ----------------
__global__ __launch_bounds__(256) void conv_vt_kernel(
    const float* __restrict__ V, unsigned short* __restrict__ Vt)
{
    const int s0 = blockIdx.x * 64;
    const int bh = blockIdx.y;
    __shared__ unsigned short T[64][66];      // [s][d], padded stride
    const int t = threadIdx.x;
    {
        const int r = t >> 2, seg = t & 3;
        const float* src = V + ((size_t)bh * SDIM + s0 + r) * DDIM + seg * 16;
        float4 f0 = ((const float4*)src)[0];
        float4 f1 = ((const float4*)src)[1];
        float4 f2 = ((const float4*)src)[2];
        float4 f3 = ((const float4*)src)[3];
        float vv[16] = { f0.x, f0.y, f0.z, f0.w, f1.x, f1.y, f1.z, f1.w,
                         f2.x, f2.y, f2.z, f2.w, f3.x, f3.y, f3.z, f3.w };
        #pragma unroll
        for (int j = 0; j < 16; ++j) T[r][seg * 16 + j] = f2bf(vv[j]);
    }
    __syncthreads();
    {
        const int d = t >> 2, q = t & 3;
        US8 w0, w1;
        #pragma unroll
        for (int j = 0; j < 8; ++j) { w0.u[j] = T[q * 16 + j][d]; w1.u[j] = T[q * 16 + 8 + j][d]; }
        unsigned short* dst = Vt + ((size_t)bh * DDIM + d) * SDIM + s0 + q * 16;
        *(uint4*)dst       = w0.v;
        *(uint4*)(dst + 8) = w1.v;
    }
}

// ================= 32x32 swapped QK^T, in-register softmax (verified core) =================
__device__ __forceinline__ void compute32(
    const unsigned char* __restrict__ Kt, const unsigned char* __restrict__ Vt,
    const FragU* __restrict__ qf, f32x16& o0, f32x16& o1, f32x16& lacc,
    float& m_s, int q_lane, int q0w, int kt64, int l31, int hi)
{
    const int swz = (l31 & 7) << 4;
    const int cb  = hi * 16;

    f32x16 s0 = {}, s1 = {};
    __builtin_amdgcn_s_setprio(1);
    #pragma unroll
    for (int kc = 0; kc < 4; ++kc) {
        FragU k0f, k1f;
        k0f.u4 = *(const uint4*)&Kt[ l31       * 128 + ((kc * 32 + cb) ^ swz)];
        k1f.u4 = *(const uint4*)&Kt[(l31 + 32) * 128 + ((kc * 32 + cb) ^ swz)];
        s0 = __builtin_amdgcn_mfma_f32_32x32x16_bf16(k0f.b, qf[kc].b, s0, 0, 0, 0);
        s1 = __builtin_amdgcn_mfma_f32_32x32x16_bf16(k1f.b, qf[kc].b, s1, 0, 0, 0);
    }
    __builtin_amdgcn_s_setprio(0);

    if (kt64 + 63 > q0w) {
        #pragma unroll
        for (int r = 0; r < 16; ++r) {
            const int kl = (r & 3) + 8 * (r >> 2) + 4 * hi;
            if (kt64 + kl      > q_lane) s0[r] = -1e30f;
            if (kt64 + 32 + kl > q_lane) s1[r] = -1e30f;
        }
    }

    float m4[4];
    #pragma unroll
    for (int j = 0; j < 4; ++j)
        m4[j] = fmaxf(fmaxf(fmaxf(s0[4*j], s0[4*j+1]), fmaxf(s0[4*j+2], s0[4*j+3])),
                      fmaxf(fmaxf(s1[4*j], s1[4*j+1]), fmaxf(s1[4*j+2], s1[4*j+3])));
    float tmx = fmaxf(fmaxf(m4[0], m4[1]), fmaxf(m4[2], m4[3]));
    tmx = fmaxf(tmx, __shfl_xor(tmx, 32, 64));

    float mn = m_s;
    if (!__all(tmx <= m_s + 8.0f)) {
        mn = fmaxf(m_s, tmx);
        const float cf = fexp2(m_s - mn);
        m_s = mn;
        #pragma unroll
        for (int r = 0; r < 16; ++r) { o0[r] *= cf; o1[r] *= cf; lacc[r] *= cf; }
    }
    #pragma unroll
    for (int r = 0; r < 16; ++r) { s0[r] = fexp2(s0[r] - mn); s1[r] = fexp2(s1[r] - mn); }
    #pragma unroll
    for (int r = 0; r < 16; ++r) lacc[r] += s0[r] + s1[r];

    FragU pa[4];
    const bool lo = (hi == 0);
    #pragma unroll
    for (int h = 0; h < 2; ++h) {
        #pragma unroll
        for (int sub = 0; sub < 2; ++sub) {
            const int e = sub * 8;
            unsigned int a0, a1, b0, b1;
            if (h == 0) {
                a0 = packbf(s0[e+0], s0[e+1]); a1 = packbf(s0[e+2], s0[e+3]);
                b0 = packbf(s0[e+4], s0[e+5]); b1 = packbf(s0[e+6], s0[e+7]);
            } else {
                a0 = packbf(s1[e+0], s1[e+1]); a1 = packbf(s1[e+2], s1[e+3]);
                b0 = packbf(s1[e+4], s1[e+5]); b1 = packbf(s1[e+6], s1[e+7]);
            }
            const unsigned int ta0 = (unsigned int)__shfl_xor((int)a0, 32, 64);
            const unsigned int ta1 = (unsigned int)__shfl_xor((int)a1, 32, 64);
            const unsigned int tb0 = (unsigned int)__shfl_xor((int)b0, 32, 64);
            const unsigned int tb1 = (unsigned int)__shfl_xor((int)b1, 32, 64);
            FragU f;
            f.u4.x = lo ? a0  : tb0;
            f.u4.y = lo ? a1  : tb1;
            f.u4.z = lo ? ta0 : b0;
            f.u4.w = lo ? ta1 : b1;
            pa[h * 2 + sub] = f;
        }
    }

    __builtin_amdgcn_s_setprio(1);
    #pragma unroll
    for (int kc = 0; kc < 4; ++kc) {
        FragU v0f, v1f;
        v0f.u4 = *(const uint4*)&Vt[ l31       * 128 + ((kc * 32 + cb) ^ swz)];
        v1f.u4 = *(const uint4*)&Vt[(l31 + 32) * 128 + ((kc * 32 + cb) ^ swz)];
        o0 = __builtin_amdgcn_mfma_f32_32x32x16_bf16(v0f.b, pa[kc].b, o0, 0, 0, 0);
        o1 = __builtin_amdgcn_mfma_f32_32x32x16_bf16(v1f.b, pa[kc].b, o1, 0, 0, 0);
    }
    __builtin_amdgcn_s_setprio(0);
}

// ======= v12: v11 + HW exp2 (v_exp_f32) everywhere =======
__global__ __launch_bounds__(512, 2) void attn_fwd_v12(
    const float* __restrict__ Q, const unsigned short* __restrict__ Kbf,
    const unsigned short* __restrict__ Vtb, float* __restrict__ O)
{
    const int bx = blockIdx.x;            // 0..7
    const int bh = blockIdx.y;
    const int qtA = bx;                   // 128-row tiles
    const int qtB = 15 - bx;
    const int nB  = 32 - 2 * bx;          // B kv-tiles (18..32); nA = 34-nB
    const int tid  = threadIdx.x;
    const int wid  = tid >> 6;            // 0..7
    const int wg   = wid & 3;             // strip 0..3 (32 q rows)
    const int gid  = wid >> 2;            // unit-half 0/1
    const int lane = tid & 63;
    const int l31  = lane & 31;
    const int hi   = lane >> 5;

    __shared__ unsigned char Sta[4][16384];   // [gid*2+parity][ K 8KB | V 8KB ]
    __shared__ float Ml[2][4][64];

    const size_t base = (size_t)bh * SDIM * DDIM;
    const int q0A = qtA * 128 + wg * 32;
    const int q0B = qtB * 128 + wg * 32;
    const int qAl = q0A + l31, qBl = q0B + l31;

    const float qs = 0.125f * 1.44269504088896f;
    FragU qfA[4], qfB[4];
    #pragma unroll
    for (int kc = 0; kc < 4; ++kc) {
        const int d0 = kc * 16 + hi * 8;
        const float* pA = Q + base + (size_t)qAl * DDIM + d0;
        const float* pB = Q + base + (size_t)qBl * DDIM + d0;
        float4 xa = ((const float4*)pA)[0], ya = ((const float4*)pA)[1];
        float4 xb = ((const float4*)pB)[0], yb = ((const float4*)pB)[1];
        qfA[kc].u4 = make_uint4(packbf(xa.x*qs, xa.y*qs), packbf(xa.z*qs, xa.w*qs),
                                packbf(ya.x*qs, ya.y*qs), packbf(ya.z*qs, ya.w*qs));
        qfB[kc].u4 = make_uint4(packbf(xb.x*qs, xb.y*qs), packbf(xb.z*qs, xb.w*qs),
                                packbf(yb.x*qs, yb.y*qs), packbf(yb.z*qs, yb.w*qs));
    }

    f32x16 oA0 = {}, oA1 = {}, laccA = {};
    f32x16 oB0 = {}, oB1 = {}, laccB = {};
    float mA = -1e30f, mB = -1e30f;

    const char* Vg = (const char*)(Vtb + (size_t)bh * DDIM * SDIM);
    auto stage = [&](int k0, int pb) {        // k0 = kv row base
        const char* Kt = (const char*)(Kbf + ((size_t)bh * SDIM + (size_t)k0) * DDIM);
        unsigned char* buf = &Sta[gid * 2 + pb][0];
        #pragma unroll
        for (int c = 0; c < 2; ++c) {
            const int lb = wg * 2048 + c * 1024;               // wave-uniform LDS base
            const int db = lb + lane * 16;
            const int sw = ((db >> 7) & 7) << 4;
            gload16(Kt + (db ^ sw), buf + lb);
            const int d  = db >> 7;
            const int wo = (db & 127) ^ sw;
            gload16(Vg + (size_t)d * (SDIM * 2) + (size_t)k0 * 2 + wo, buf + 8192 + lb);
        }
    };

    // unit u (0..33): u < nB -> tile B kv-tile u ; else tile A kv-tile u-nB.
    const int ubase = gid * 17;
    stage(((ubase < nB) ? ubase : ubase - nB) * 64, 0);
    int pb = 0;
    for (int i = 0; i < 17; ++i) {
        __syncthreads();                       // staged loads landed; prior reads done
        if (i + 1 < 17) {
            const int un = ubase + i + 1;
            stage(((un < nB) ? un : un - nB) * 64, pb ^ 1);
        }
        const int u = ubase + i;
        const unsigned char* Kb_ = &Sta[gid * 2 + pb][0];
        const unsigned char* Vb_ = &Sta[gid * 2 + pb][8192];
        if (u < nB) {
            const int kt64 = u * 64;
            if (kt64 <= q0B + 31)
                compute32(Kb_, Vb_, qfB, oB0, oB1, laccB, mB, qBl, q0B, kt64, l31, hi);
        } else {
            const int kt64 = (u - nB) * 64;
            if (kt64 <= q0A + 31)
                compute32(Kb_, Vb_, qfA, oA0, oA1, laccA, mA, qAl, q0A, kt64, l31, hi);
        }
        pb ^= 1;
    }

    // ---- per-wave l row-sums ----
    float lB = ((laccB[0]+laccB[1])+(laccB[2]+laccB[3])) + ((laccB[4]+laccB[5])+(laccB[6]+laccB[7]))
             + ((laccB[8]+laccB[9])+(laccB[10]+laccB[11])) + ((laccB[12]+laccB[13])+(laccB[14]+laccB[15]));
    lB += __shfl_xor(lB, 32, 64);
    float lA = ((laccA[0]+laccA[1])+(laccA[2]+laccA[3])) + ((laccA[4]+laccA[5])+(laccA[6]+laccA[7]))
             + ((laccA[8]+laccA[9])+(laccA[10]+laccA[11])) + ((laccA[12]+laccA[13])+(laccA[14]+laccA[15]));
    lA += __shfl_xor(lA, 32, 64);

    float* Ob = (float*)&Sta[0][0];           // 32 KB scratch for one tile's partial O
    const int ib = wg * 64 + lane;

    // ---- merge tile B ----
    __syncthreads();
    if (gid == 1) {
        Ml[0][wg][lane] = mB;
        Ml[1][wg][lane] = lB;
        #pragma unroll
        for (int j = 0; j < 16; ++j) {
            Ob[ j       * 256 + ib] = oB0[j];
            Ob[(j + 16) * 256 + ib] = oB1[j];
        }
    }
    __syncthreads();
    if (gid == 0) {
        const float m2 = Ml[0][wg][lane];
        const float l2 = Ml[1][wg][lane];
        const float m  = fmaxf(mB, m2);
        const float c1 = fexp2(mB - m);
        const float c2 = fexp2(m2 - m);
        const float inv = 1.f / (lB * c1 + l2 * c2);
        #pragma unroll
        for (int mq = 0; mq < 4; ++mq) {
            const int dm = mq * 8 + hi * 4;
            float4 w;
            w.x = (oB0[4*mq+0]*c1 + Ob[(4*mq+0)*256 + ib]*c2) * inv;
            w.y = (oB0[4*mq+1]*c1 + Ob[(4*mq+1)*256 + ib]*c2) * inv;
            w.z = (oB0[4*mq+2]*c1 + Ob[(4*mq+2)*256 + ib]*c2) * inv;
            w.w = (oB0[4*mq+3]*c1 + Ob[(4*mq+3)*256 + ib]*c2) * inv;
            *(float4*)(O + base + (size_t)qBl * DDIM + dm) = w;
            w.x = (oB1[4*mq+0]*c1 + Ob[(16+4*mq+0)*256 + ib]*c2) * inv;
            w.y = (oB1[4*mq+1]*c1 + Ob[(16+4*mq+1)*256 + ib]*c2) * inv;
            w.z = (oB1[4*mq+2]*c1 + Ob[(16+4*mq+2)*256 + ib]*c2) * inv;
            w.w = (oB1[4*mq+3]*c1 + Ob[(16+4*mq+3)*256 + ib]*c2) * inv;
            *(float4*)(O + base + (size_t)qBl * DDIM + 32 + dm) = w;
        }
    }

    // ---- merge tile A ----
    __syncthreads();
    if (gid == 1) {
        Ml[0][wg][lane] = mA;
        Ml[1][wg][lane] = lA;
        #pragma unroll
        for (int j = 0; j < 16; ++j) {
            Ob[ j       * 256 + ib] = oA0[j];
            Ob[(j + 16) * 256 + ib] = oA1[j];
        }
    }
    __syncthreads();
    if (gid == 0) {
        const float m2 = Ml[0][wg][lane];
        const float l2 = Ml[1][wg][lane];
        const float m  = fmaxf(mA, m2);
        const float c1 = fexp2(mA - m);
        const float c2 = fexp2(m2 - m);
        const float inv = 1.f / (lA * c1 + l2 * c2);
        #pragma unroll
        for (int mq = 0; mq < 4; ++mq) {
            const int dm = mq * 8 + hi * 4;
            float4 w;
            w.x = (oA0[4*mq+0]*c1 + Ob[(4*mq+0)*256 + ib]*c2) * inv;
            w.y = (oA0[4*mq+1]*c1 + Ob[(4*mq+1)*256 + ib]*c2) * inv;
            w.z = (oA0[4*mq+2]*c1 + Ob[(4*mq+2)*256 + ib]*c2) * inv;
            w.w = (oA0[4*mq+3]*c1 + Ob[(4*mq+3)*256 + ib]*c2) * inv;
            *(float4*)(O + base + (size_t)qAl * DDIM + dm) = w;
            w.x = (oA1[4*mq+0]*c1 + Ob[(16+4*mq+0)*256 + ib]*c2) * inv;
            w.y = (oA1[4*mq+1]*c1 + Ob[(16+4*mq+1)*256 + ib]*c2) * inv;
            w.z = (oA1[4*mq+2]*c1 + Ob[(16+4*mq+2)*256 + ib]*c2) * inv;
            w.w = (oA1[4*mq+3]*c1 + Ob[(16+4*mq+3)*256 + ib]*c2) * inv;
            *(float4*)(O + base + (size_t)qAl * DDIM + 32 + dm) = w;
        }
    }
}

// ---------------- round-1-style fallback (used only if ws too small) ----------------
__global__ __launch_bounds__(256) void attn_fwd_v1(
    const float* __restrict__ Q, const float* __restrict__ K,
    const float* __restrict__ V, float* __restrict__ O)
{
    const int qt   = blockIdx.x;
    const int bh   = blockIdx.y;
    const int tid  = threadIdx.x;
    const int wid  = tid >> 6;
    const int lane = tid & 63;
    const int l15  = lane & 15;
    const int g    = lane >> 4;

    __shared__ unsigned char Klds[64 * 128];
    __shared__ unsigned char Vt[64 * 128];
    __shared__ unsigned char Pl[4][2048];

    const size_t base = (size_t)bh * SDIM * DDIM;
    const int rw0 = qt * 64 + wid * 16;

    FragU qa[2];
    {
        const float* qp = Q + base + (size_t)(rw0 + l15) * DDIM;
        #pragma unroll
        for (int kc = 0; kc < 2; ++kc) {
            const float4* pp = (const float4*)(qp + kc * 32 + g * 8);
            float4 x = pp[0], y = pp[1];
            float f[8] = { x.x, x.y, x.z, x.w, y.x, y.y, y.z, y.w };
            #pragma unroll
            for (int j = 0; j < 8; ++j) qa[kc].s[j] = (short)f2bf(f[j] * 0.125f);
        }
    }

    f32x4 o[4] = {};
    float m_i[4], l_i[4];
    #pragma unroll
    for (int i = 0; i < 4; ++i) { m_i[i] = -1e30f; l_i[i] = 0.f; }

    for (int kt = 0; kt <= qt; ++kt) {
        const int k0 = kt * 64;
        __syncthreads();
        {
            const int row = tid >> 2, seg = tid & 3;
            const float* src = K + base + (size_t)(k0 + row) * DDIM + seg * 16;
            float4 f0 = ((const float4*)src)[0];
            float4 f1 = ((const float4*)src)[1];
            float4 f2 = ((const float4*)src)[2];
            float4 f3 = ((const float4*)src)[3];
            US8 c0, c1;
            c0.u[0]=f2bf(f0.x); c0.u[1]=f2bf(f0.y); c0.u[2]=f2bf(f0.z); c0.u[3]=f2bf(f0.w);
            c0.u[4]=f2bf(f1.x); c0.u[5]=f2bf(f1.y); c0.u[6]=f2bf(f1.z); c0.u[7]=f2bf(f1.w);
            c1.u[0]=f2bf(f2.x); c1.u[1]=f2bf(f2.y); c1.u[2]=f2bf(f2.z); c1.u[3]=f2bf(f2.w);
            c1.u[4]=f2bf(f3.x); c1.u[5]=f2bf(f3.y); c1.u[6]=f2bf(f3.z); c1.u[7]=f2bf(f3.w);
            const int rb = row * 128 + seg * 32;
            const int sw = (row & 7) << 4;
            *(uint4*)&Klds[(rb)      ^ sw] = c0.v;
            *(uint4*)&Klds[(rb + 16) ^ sw] = c1.v;
        }
        {
            const int kv = tid >> 2, seg = tid & 3;
            const float* src = V + base + (size_t)(k0 + kv) * DDIM + seg * 16;
            float4 f0 = ((const float4*)src)[0];
            float4 f1 = ((const float4*)src)[1];
            float4 f2 = ((const float4*)src)[2];
            float4 f3 = ((const float4*)src)[3];
            float vv[16] = { f0.x, f0.y, f0.z, f0.w, f1.x, f1.y, f1.z, f1.w,
                             f2.x, f2.y, f2.z, f2.w, f3.x, f3.y, f3.z, f3.w };
            #pragma unroll
            for (int j = 0; j < 16; ++j) {
                const int dd = seg * 16 + j;
                const int by = dd * 128 + kv * 2;
                *(unsigned short*)&Vt[by ^ ((dd & 7) << 4)] = f2bf(vv[j]);
            }
        }
        __syncthreads();

        f32x4 s[4];
        #pragma unroll
        for (int ct = 0; ct < 4; ++ct) {
            f32x4 acc = {};
            #pragma unroll
            for (int kc = 0; kc < 2; ++kc) {
                const int row = ct * 16 + l15;
                FragU kb;
                kb.u4 = *(const uint4*)&Klds[(row * 128 + (kc * 32 + g * 8) * 2) ^ ((row & 7) << 4)];
                acc = __builtin_amdgcn_mfma_f32_16x16x32_bf16(qa[kc].b, kb.b, acc, 0, 0, 0);
            }
            s[ct] = acc;
        }
        if (kt == qt) {
            #pragma unroll
            for (int ct = 0; ct < 4; ++ct)
                #pragma unroll
                for (int i = 0; i < 4; ++i)
                    if (k0 + ct * 16 + l15 > rw0 + g * 4 + i) s[ct][i] = -1e30f;
        }
        float tm[4];
        #pragma unroll
        for (int i = 0; i < 4; ++i)
            tm[i] = fmaxf(fmaxf(s[0][i], s[1][i]), fmaxf(s[2][i], s[3][i]));
        #pragma unroll
        for (int off = 1; off < 16; off <<= 1)
            #pragma unroll
            for (int i = 0; i < 4; ++i) tm[i] = fmaxf(tm[i], __shfl_xor(tm[i], off, 64));
        float cf[4];
        #pragma unroll
        for (int i = 0; i < 4; ++i) {
            const float mn = fmaxf(m_i[i], tm[i]);
            cf[i] = __expf(m_i[i] - mn);
            m_i[i] = mn;
        }
        #pragma unroll
        for (int ct = 0; ct < 4; ++ct)
            #pragma unroll
            for (int i = 0; i < 4; ++i) s[ct][i] = __expf(s[ct][i] - m_i[i]);
        float rsv[4];
        #pragma unroll
        for (int i = 0; i < 4; ++i) rsv[i] = s[0][i] + s[1][i] + s[2][i] + s[3][i];
        #pragma unroll
        for (int off = 1; off < 16; off <<= 1)
            #pragma unroll
            for (int i = 0; i < 4; ++i) rsv[i] += __shfl_xor(rsv[i], off, 64);
        #pragma unroll
        for (int i = 0; i < 4; ++i) l_i[i] = l_i[i] * cf[i] + rsv[i];
        #pragma unroll
        for (int n = 0; n < 4; ++n)
            #pragma unroll
            for (int i = 0; i < 4; ++i) o[n][i] *= cf[i];

        unsigned char* pw = Pl[wid];
        #pragma unroll
        for (int ct = 0; ct < 4; ++ct)
            #pragma unroll
            for (int i = 0; i < 4; ++i) {
                const int row = g * 4 + i;
                const int by  = row * 128 + (ct * 16 + l15) * 2;
                *(unsigned short*)&pw[by ^ ((row & 7) << 4)] = f2bf(s[ct][i]);
            }
        asm volatile("s_waitcnt lgkmcnt(0)" ::: "memory");
        __builtin_amdgcn_sched_barrier(0);

        #pragma unroll
        for (int kc = 0; kc < 2; ++kc) {
            FragU pafr;
            pafr.u4 = *(const uint4*)&pw[(l15 * 128 + (kc * 32 + g * 8) * 2) ^ ((l15 & 7) << 4)];
            #pragma unroll
            for (int nt = 0; nt < 4; ++nt) {
                const int row = nt * 16 + l15;
                FragU vb;
                vb.u4 = *(const uint4*)&Vt[(row * 128 + (kc * 32 + g * 8) * 2) ^ ((row & 7) << 4)];
                o[nt] = __builtin_amdgcn_mfma_f32_16x16x32_bf16(pafr.b, vb.b, o[nt], 0, 0, 0);
            }
        }
    }

    #pragma unroll
    for (int i = 0; i < 4; ++i) {
        const float inv = 1.0f / l_i[i];
        float* op = O + base + (size_t)(rw0 + g * 4 + i) * DDIM;
        #pragma unroll
        for (int n = 0; n < 4; ++n) op[n * 16 + l15] = o[n][i] * inv;
    }
}

extern "C" void kernel_launch(void* const* d_in, const int* in_sizes, int n_in,
                              void* d_out, int out_size, void* d_ws, size_t ws_size,
                              hipStream_t stream) {
    const float* Q = (const float*)d_in[0];
    const float* K = (const float*)d_in[1];
    const float* V = (const float*)d_in[2];
    float* O = (float*)d_out;

    const size_t tensor_elems = (size_t)BHN * SDIM * DDIM;      // 4.19M
    const size_t need = tensor_elems * 2 * 2;                   // Kbf + Vt, bf16

    if (ws_size >= need) {
        unsigned short* Kb = (unsigned short*)d_ws;
        unsigned short* Vt = Kb + tensor_elems;
        conv_k_kernel<<<dim3((unsigned)(tensor_elems / 8 / 256)), dim3(256), 0, stream>>>(K, Kb);
        conv_vt_kernel<<<dim3(SDIM / 64, BHN), dim3(256), 0, stream>>>(V, Vt);
        attn_fwd_v12<<<dim3(8, BHN), dim3(512), 0, stream>>>(Q, Kb, Vt, O);
    } else {
        attn_fwd_v1<<<dim3(NQT, BHN), dim3(256), 0, stream>>>(Q, K, V, O);
    }
}